// Round 1
// baseline (4135.036 us; speedup 1.0000x reference)
//
#include <hip/hip_runtime.h>
#include <math.h>

// GCNII forward: N=100000 nodes, E=1.6M edges, F_IN=300, H=64, OUT=20, L=8
// Baseline: fp32, atomic scatter-add SpMM, vector-ALU GEMMs.

#define HID 64
#define FIN 300
#define NOUT 20
#define ALPHA 0.1f

// ---- degree / norm ----------------------------------------------------
__global__ void deg_init(float* __restrict__ deg, int n) {
    int i = blockIdx.x * blockDim.x + threadIdx.x;
    if (i < n) deg[i] = 1.0f;  // self-loop weight
}

__global__ void deg_accum(const int* __restrict__ col, const float* __restrict__ w,
                          float* __restrict__ deg, int e) {
    int i = blockIdx.x * blockDim.x + threadIdx.x;
    if (i < e) atomicAdd(&deg[col[i]], w[i]);
}

__global__ void dinv_k(const float* __restrict__ deg, float* __restrict__ dinv, int n) {
    int i = blockIdx.x * blockDim.x + threadIdx.x;
    if (i < n) {
        float d = deg[i];
        dinv[i] = (d > 0.0f) ? rsqrtf(d) : 0.0f;
    }
}

// ---- input GEMM: h0 = relu(x @ W_in + b_in)  [N,300]@[300,64] ---------
__global__ __launch_bounds__(256) void gemm_in(const float* __restrict__ x,
                                               const float* __restrict__ Win,
                                               const float* __restrict__ bin,
                                               float* __restrict__ h0, int n) {
    int lane = threadIdx.x & 63;
    int node = blockIdx.x * 4 + (threadIdx.x >> 6);
    if (node >= n) return;
    const float* xr = x + (size_t)node * FIN;  // 1200B rows -> 16B aligned
    float acc = 0.0f;
    for (int k = 0; k < FIN; k += 4) {
        float4 xv = *reinterpret_cast<const float4*>(xr + k);
        acc = fmaf(xv.x, Win[(k + 0) * HID + lane], acc);
        acc = fmaf(xv.y, Win[(k + 1) * HID + lane], acc);
        acc = fmaf(xv.z, Win[(k + 2) * HID + lane], acc);
        acc = fmaf(xv.w, Win[(k + 3) * HID + lane], acc);
    }
    acc += bin[lane];
    h0[(size_t)node * HID + lane] = fmaxf(acc, 0.0f);
}

// ---- z = alpha*x0 + (1-alpha)*(selfloop contribution), then edges add --
__global__ void z_init(const float* __restrict__ x0, const float* __restrict__ hsrc,
                       const float* __restrict__ dinv, float* __restrict__ z, int n) {
    int idx = blockIdx.x * blockDim.x + threadIdx.x;
    if (idx >= n * HID) return;
    int node = idx >> 6;
    float di = dinv[node];
    z[idx] = ALPHA * x0[idx] + (1.0f - ALPHA) * di * di * hsrc[idx];
}

__global__ __launch_bounds__(256) void edge_agg(const int* __restrict__ row,
                                                const int* __restrict__ col,
                                                const float* __restrict__ w,
                                                const float* __restrict__ dinv,
                                                const float* __restrict__ hsrc,
                                                float* __restrict__ z, int e) {
    int lane = threadIdx.x & 63;
    int eid = blockIdx.x * 4 + (threadIdx.x >> 6);
    if (eid >= e) return;
    int r = row[eid];
    int c = col[eid];
    float nr = (1.0f - ALPHA) * dinv[r] * w[eid] * dinv[c];
    atomicAdd(&z[(size_t)c * HID + lane], nr * hsrc[(size_t)r * HID + lane]);
}

// ---- per-layer GEMM: h = relu((1-beta)*z + beta*(z @ Wl)) -------------
__global__ __launch_bounds__(256) void gemm_layer(const float* __restrict__ z,
                                                  const float* __restrict__ Wl,
                                                  float* __restrict__ h,
                                                  float beta, int n) {
    int lane = threadIdx.x & 63;
    int node = blockIdx.x * 4 + (threadIdx.x >> 6);
    if (node >= n) return;
    const float* zr = z + (size_t)node * HID;
    float acc = 0.0f;
#pragma unroll
    for (int k = 0; k < HID; k += 4) {
        float4 zv = *reinterpret_cast<const float4*>(zr + k);
        acc = fmaf(zv.x, Wl[(k + 0) * HID + lane], acc);
        acc = fmaf(zv.y, Wl[(k + 1) * HID + lane], acc);
        acc = fmaf(zv.z, Wl[(k + 2) * HID + lane], acc);
        acc = fmaf(zv.w, Wl[(k + 3) * HID + lane], acc);
    }
    float zi = zr[lane];
    h[(size_t)node * HID + lane] = fmaxf((1.0f - beta) * zi + beta * acc, 0.0f);
}

// ---- output GEMM: out = h @ W_out + b_out  [N,64]@[64,20] -------------
__global__ void gemm_out(const float* __restrict__ h, const float* __restrict__ Wout,
                         const float* __restrict__ bout, float* __restrict__ out, int n) {
    int idx = blockIdx.x * blockDim.x + threadIdx.x;
    if (idx >= n * NOUT) return;
    int node = idx / NOUT;
    int o = idx - node * NOUT;
    const float* hr = h + (size_t)node * HID;
    float acc = bout[o];
#pragma unroll
    for (int k = 0; k < HID; ++k) acc = fmaf(hr[k], Wout[k * NOUT + o], acc);
    out[idx] = acc;
}

extern "C" void kernel_launch(void* const* d_in, const int* in_sizes, int n_in,
                              void* d_out, int out_size, void* d_ws, size_t ws_size,
                              hipStream_t stream) {
    const float* x    = (const float*)d_in[0];
    const int*   ei   = (const int*)d_in[1];
    const float* ew   = (const float*)d_in[2];
    const float* Win  = (const float*)d_in[3];
    const float* bin  = (const float*)d_in[4];
    const float* cw   = (const float*)d_in[5];
    const float* Wout = (const float*)d_in[6];
    const float* bout = (const float*)d_in[7];

    const int n = in_sizes[0] / FIN;          // 100000
    const int e = in_sizes[2];                // 1600000
    const int L = in_sizes[5] / (HID * HID);  // 8
    const int* row = ei;
    const int* col = ei + e;

    char* p = (char*)d_ws;
    float* deg  = (float*)p; p += (size_t)n * sizeof(float);
    float* dinv = (float*)p; p += (size_t)n * sizeof(float);
    float* x0   = (float*)p; p += (size_t)n * HID * sizeof(float);
    float* h    = (float*)p; p += (size_t)n * HID * sizeof(float);
    float* z    = (float*)p; p += (size_t)n * HID * sizeof(float);

    deg_init<<<(n + 255) / 256, 256, 0, stream>>>(deg, n);
    deg_accum<<<(e + 255) / 256, 256, 0, stream>>>(col, ew, deg, e);
    dinv_k<<<(n + 255) / 256, 256, 0, stream>>>(deg, dinv, n);

    gemm_in<<<(n + 3) / 4, 256, 0, stream>>>(x, Win, bin, x0, n);

    const float* src = x0;
    for (int l = 0; l < L; ++l) {
        float beta = (float)log(0.5 / (double)(l + 1) + 1.0);
        z_init<<<((size_t)n * HID + 255) / 256, 256, 0, stream>>>(x0, src, dinv, z, n);
        edge_agg<<<(e + 3) / 4, 256, 0, stream>>>(row, col, ew, dinv, src, z, e);
        gemm_layer<<<(n + 3) / 4, 256, 0, stream>>>(z, cw + (size_t)l * HID * HID, h, beta, n);
        src = h;
    }
    gemm_out<<<((size_t)n * NOUT + 255) / 256, 256, 0, stream>>>(h, Wout, bout, (float*)d_out, n);
}

// Round 2
// 1422.753 us; speedup vs baseline: 2.9064x; 2.9064x over previous
//
#include <hip/hip_runtime.h>
#include <hip/hip_fp16.h>
#include <hip/hip_bf16.h>
#include <math.h>

// GCNII forward: N=100000, E=1.6M, F_IN=300, H=64, OUT=20, L=8
// Round 2: CSR-based gather SpMM fused with per-layer GEMM (W in VGPRs),
// LDS-staged input GEMM, fp16 edge norms, bf16 x0 residual copy.

#define HID 64
#define FIN 300
#define NOUT 20
#define ALPHA 0.1f

// ---- init: deg=1 (self loop), counts=0 --------------------------------
__global__ void init_k(float* __restrict__ deg, int* __restrict__ counts, int n) {
    int i = blockIdx.x * blockDim.x + threadIdx.x;
    if (i < n) { deg[i] = 1.0f; counts[i] = 0; }
}

// ---- accumulate weighted degree + in-degree counts --------------------
__global__ void accum_k(const int* __restrict__ col, const float* __restrict__ w,
                        float* __restrict__ deg, int* __restrict__ counts, int e) {
    int i = blockIdx.x * blockDim.x + threadIdx.x;
    if (i < e) {
        int c = col[i];
        atomicAdd(&deg[c], w[i]);
        atomicAdd(&counts[c], 1);
    }
}

// ---- dinv in place ----------------------------------------------------
__global__ void dinv_k(float* __restrict__ deg, int n) {
    int i = blockIdx.x * blockDim.x + threadIdx.x;
    if (i < n) { float d = deg[i]; deg[i] = (d > 0.0f) ? rsqrtf(d) : 0.0f; }
}

// ---- scan stage 1: per-block sums of counts ---------------------------
__global__ __launch_bounds__(1024) void scan1_k(const int* __restrict__ counts,
                                                int* __restrict__ bsum, int n) {
    __shared__ int s[1024];
    int t = threadIdx.x, i = blockIdx.x * 1024 + t;
    s[t] = (i < n) ? counts[i] : 0;
    __syncthreads();
    for (int off = 512; off > 0; off >>= 1) {
        if (t < off) s[t] += s[t + off];
        __syncthreads();
    }
    if (t == 0) bsum[blockIdx.x] = s[0];
}

// ---- scan stage 2: serial exclusive scan of block sums (nb ~ 98) ------
__global__ void scan2_k(int* __restrict__ bsum, int nb, int* __restrict__ rp,
                        int n, int e) {
    if (blockIdx.x == 0 && threadIdx.x == 0) {
        int acc = 0;
        for (int b = 0; b < nb; ++b) { int v = bsum[b]; bsum[b] = acc; acc += v; }
        rp[n] = e;
    }
}

// ---- scan stage 3: in-block exclusive scan -> row_ptr; zero cursor ----
__global__ __launch_bounds__(1024) void scan3_k(int* __restrict__ counts,
                                                const int* __restrict__ bsum,
                                                int* __restrict__ rp, int n) {
    __shared__ int s[1024];
    int t = threadIdx.x, i = blockIdx.x * 1024 + t;
    int v = (i < n) ? counts[i] : 0;
    s[t] = v;
    __syncthreads();
    for (int off = 1; off < 1024; off <<= 1) {
        int u = (t >= off) ? s[t - off] : 0;
        __syncthreads();
        s[t] += u;
        __syncthreads();
    }
    if (i < n) { rp[i] = bsum[blockIdx.x] + s[t] - v; counts[i] = 0; }
}

// ---- fill CSR: srcs + fp16 norm weights (includes (1-alpha)) ----------
__global__ void fill_k(const int* __restrict__ row, const int* __restrict__ col,
                       const float* __restrict__ ew, const float* __restrict__ dinv,
                       const int* __restrict__ rp, int* __restrict__ cursor,
                       int* __restrict__ srcs, __half* __restrict__ wgt, int e) {
    int i = blockIdx.x * blockDim.x + threadIdx.x;
    if (i >= e) return;
    int c = col[i], r = row[i];
    float nw = (1.0f - ALPHA) * dinv[r] * ew[i] * dinv[c];
    int pos = rp[c] + atomicAdd(&cursor[c], 1);
    srcs[pos] = r;
    wgt[pos] = __float2half(nw);
}

// ---- input GEMM: h0 = relu(x @ W_in + b_in); also bf16 copy -----------
#define KC1 152
__global__ __launch_bounds__(256) void gemm_in_k(const float* __restrict__ x,
                                                 const float* __restrict__ Win,
                                                 const float* __restrict__ bin,
                                                 float* __restrict__ h0,
                                                 __hip_bfloat16* __restrict__ x0b,
                                                 int n) {
    __shared__ float Ws[KC1 * HID];  // 38.9 KB
    int t = threadIdx.x, lane = t & 63, wv = t >> 6;
    int node0 = blockIdx.x * 16 + wv * 4;
    int m0 = min(node0 + 0, n - 1), m1 = min(node0 + 1, n - 1);
    int m2 = min(node0 + 2, n - 1), m3 = min(node0 + 3, n - 1);
    const float* xp0 = x + (size_t)m0 * FIN;
    const float* xp1 = x + (size_t)m1 * FIN;
    const float* xp2 = x + (size_t)m2 * FIN;
    const float* xp3 = x + (size_t)m3 * FIN;
    float a0 = 0, a1 = 0, a2 = 0, a3 = 0;
    for (int c = 0; c < 2; ++c) {
        int kb = c * KC1;
        int klen = c ? (FIN - KC1) : KC1;  // 152, 148
        __syncthreads();
        for (int i = t; i < klen * HID; i += 256) Ws[i] = Win[kb * HID + i];
        __syncthreads();
        for (int k = 0; k < klen; k += 4) {
            float4 v0 = *reinterpret_cast<const float4*>(xp0 + kb + k);
            float4 v1 = *reinterpret_cast<const float4*>(xp1 + kb + k);
            float4 v2 = *reinterpret_cast<const float4*>(xp2 + kb + k);
            float4 v3 = *reinterpret_cast<const float4*>(xp3 + kb + k);
            const float* w = &Ws[k * HID + lane];
            float w0 = w[0], w1 = w[64], w2 = w[128], w3 = w[192];
            a0 = fmaf(v0.x, w0, a0); a1 = fmaf(v1.x, w0, a1);
            a2 = fmaf(v2.x, w0, a2); a3 = fmaf(v3.x, w0, a3);
            a0 = fmaf(v0.y, w1, a0); a1 = fmaf(v1.y, w1, a1);
            a2 = fmaf(v2.y, w1, a2); a3 = fmaf(v3.y, w1, a3);
            a0 = fmaf(v0.z, w2, a0); a1 = fmaf(v1.z, w2, a1);
            a2 = fmaf(v2.z, w2, a2); a3 = fmaf(v3.z, w2, a3);
            a0 = fmaf(v0.w, w3, a0); a1 = fmaf(v1.w, w3, a1);
            a2 = fmaf(v2.w, w3, a2); a3 = fmaf(v3.w, w3, a3);
        }
    }
    float b = bin[lane];
    if (node0 + 0 < n) { float r = fmaxf(a0 + b, 0.f); size_t o = (size_t)(node0 + 0) * HID + lane; h0[o] = r; x0b[o] = __float2bfloat16(r); }
    if (node0 + 1 < n) { float r = fmaxf(a1 + b, 0.f); size_t o = (size_t)(node0 + 1) * HID + lane; h0[o] = r; x0b[o] = __float2bfloat16(r); }
    if (node0 + 2 < n) { float r = fmaxf(a2 + b, 0.f); size_t o = (size_t)(node0 + 2) * HID + lane; h0[o] = r; x0b[o] = __float2bfloat16(r); }
    if (node0 + 3 < n) { float r = fmaxf(a3 + b, 0.f); size_t o = (size_t)(node0 + 3) * HID + lane; h0[o] = r; x0b[o] = __float2bfloat16(r); }
}

// ---- fused layer: gather + residual + 64x64 GEMM + relu ---------------
// one wave per node; W column in 64 VGPRs; z row broadcast via LDS.
__global__ __launch_bounds__(256, 4) void layer_k(const int* __restrict__ rp,
                                                  const int* __restrict__ srcs,
                                                  const __half* __restrict__ wgt,
                                                  const float* __restrict__ dinv,
                                                  const __hip_bfloat16* __restrict__ x0b,
                                                  const float* __restrict__ hin,
                                                  float* __restrict__ hout,
                                                  const float* __restrict__ Wl,
                                                  float beta, int n) {
    __shared__ float zs[4][64];
    int lane = threadIdx.x & 63, wv = threadIdx.x >> 6;
    float wreg[64];
#pragma unroll
    for (int k = 0; k < 64; ++k) wreg[k] = Wl[k * 64 + lane];
    int stride = gridDim.x * 4;
    for (int node = blockIdx.x * 4 + wv; node < n; node += stride) {
        size_t rowoff = (size_t)node * 64 + lane;
        float di = dinv[node];
        float z0 = fmaf(ALPHA, __bfloat162float(x0b[rowoff]),
                        (1.0f - ALPHA) * di * di * hin[rowoff]);
        float z1 = 0, z2 = 0, z3 = 0;
        int j = rp[node], end = rp[node + 1];
        for (; j + 3 < end; j += 4) {
            int s0 = srcs[j], s1 = srcs[j + 1], s2 = srcs[j + 2], s3 = srcs[j + 3];
            float w0 = __half2float(wgt[j]),     w1 = __half2float(wgt[j + 1]);
            float w2 = __half2float(wgt[j + 2]), w3 = __half2float(wgt[j + 3]);
            z0 = fmaf(w0, hin[(size_t)s0 * 64 + lane], z0);
            z1 = fmaf(w1, hin[(size_t)s1 * 64 + lane], z1);
            z2 = fmaf(w2, hin[(size_t)s2 * 64 + lane], z2);
            z3 = fmaf(w3, hin[(size_t)s3 * 64 + lane], z3);
        }
        for (; j < end; ++j)
            z0 = fmaf(__half2float(wgt[j]), hin[(size_t)srcs[j] * 64 + lane], z0);
        float z = (z0 + z1) + (z2 + z3);
        zs[wv][lane] = z;
        __builtin_amdgcn_wave_barrier();
        float g0 = 0, g1 = 0, g2 = 0, g3 = 0;
#pragma unroll
        for (int q = 0; q < 16; ++q) {
            float4 zq = *reinterpret_cast<const float4*>(&zs[wv][q * 4]);
            g0 = fmaf(zq.x, wreg[q * 4 + 0], g0);
            g1 = fmaf(zq.y, wreg[q * 4 + 1], g1);
            g2 = fmaf(zq.z, wreg[q * 4 + 2], g2);
            g3 = fmaf(zq.w, wreg[q * 4 + 3], g3);
        }
        __builtin_amdgcn_wave_barrier();
        float g = (g0 + g1) + (g2 + g3);
        hout[rowoff] = fmaxf(fmaf(beta, g, (1.0f - beta) * z), 0.0f);
    }
}

// ---- output GEMM: out = h @ W_out + b_out -----------------------------
__global__ __launch_bounds__(256) void gemm_out_k(const float* __restrict__ h,
                                                  const float* __restrict__ Wout,
                                                  const float* __restrict__ bout,
                                                  float* __restrict__ out, int n) {
    __shared__ float hs[64][65];
    __shared__ float Ws[64 * NOUT];
    __shared__ float bs[NOUT];
    int t = threadIdx.x;
    for (int i = t; i < 64 * NOUT; i += 256) Ws[i] = Wout[i];
    if (t < NOUT) bs[t] = bout[t];
    int base = blockIdx.x * 64;
    int lim = min(64, n - base);
    for (int i = t; i < 64 * 64; i += 256) {
        int r = i >> 6;
        hs[r][i & 63] = (r < lim) ? h[(size_t)(base + r) * 64 + (i & 63)] : 0.0f;
    }
    __syncthreads();
#pragma unroll
    for (int q = 0; q < 5; ++q) {
        int of = t + 256 * q;          // 0..1279
        int nd = of / NOUT, o = of - nd * NOUT;
        float acc = bs[o];
#pragma unroll
        for (int k = 0; k < 64; ++k) acc = fmaf(hs[nd][k], Ws[k * NOUT + o], acc);
        if (nd < lim) out[(size_t)(base + nd) * NOUT + o] = acc;
    }
}

extern "C" void kernel_launch(void* const* d_in, const int* in_sizes, int n_in,
                              void* d_out, int out_size, void* d_ws, size_t ws_size,
                              hipStream_t stream) {
    const float* x    = (const float*)d_in[0];
    const int*   ei   = (const int*)d_in[1];
    const float* ew   = (const float*)d_in[2];
    const float* Win  = (const float*)d_in[3];
    const float* bin  = (const float*)d_in[4];
    const float* cw   = (const float*)d_in[5];
    const float* Wout = (const float*)d_in[6];
    const float* bout = (const float*)d_in[7];

    const int n = in_sizes[0] / FIN;          // 100000
    const int e = in_sizes[2];                // 1600000
    const int L = in_sizes[5] / (HID * HID);  // 8
    const int* row = ei;
    const int* col = ei + e;

    size_t off = 0;
    auto alloc = [&](size_t bytes) -> char* {
        char* q = (char*)d_ws + off;
        off = (off + bytes + 255) & ~(size_t)255;
        return q;
    };
    __hip_bfloat16* x0b = (__hip_bfloat16*)alloc((size_t)n * HID * 2);
    float* hA    = (float*)alloc((size_t)n * HID * 4);
    float* hB    = (float*)alloc((size_t)n * HID * 4);
    int*   srcs  = (int*)alloc((size_t)e * 4);
    __half* wgt  = (__half*)alloc((size_t)e * 2);
    float* deg   = (float*)alloc((size_t)n * 4);       // becomes dinv in place
    int*   counts= (int*)alloc((size_t)n * 4);         // becomes cursor
    int*   rp    = (int*)alloc((size_t)(n + 1) * 4);
    int*   bsum  = (int*)alloc(1024 * 4);

    const int nb = (n + 1023) / 1024;

    init_k<<<(n + 255) / 256, 256, 0, stream>>>(deg, counts, n);
    accum_k<<<(e + 255) / 256, 256, 0, stream>>>(col, ew, deg, counts, e);
    dinv_k<<<(n + 255) / 256, 256, 0, stream>>>(deg, n);
    scan1_k<<<nb, 1024, 0, stream>>>(counts, bsum, n);
    scan2_k<<<1, 1, 0, stream>>>(bsum, nb, rp, n, e);
    scan3_k<<<nb, 1024, 0, stream>>>(counts, bsum, rp, n);
    fill_k<<<(e + 255) / 256, 256, 0, stream>>>(row, col, ew, deg, rp, counts, srcs, wgt, e);

    gemm_in_k<<<(n + 15) / 16, 256, 0, stream>>>(x, Win, bin, hA, x0b, n);

    const float* hin = hA;
    float* hout = hB;
    for (int l = 0; l < L; ++l) {
        float beta = (float)log(0.5 / (double)(l + 1) + 1.0);
        layer_k<<<2048, 256, 0, stream>>>(rp, srcs, wgt, deg, x0b, hin, hout,
                                          cw + (size_t)l * HID * HID, beta, n);
        const float* tmp = hin; hin = hout; hout = (float*)tmp;
    }
    gemm_out_k<<<(n + 63) / 64, 256, 0, stream>>>(hin, Wout, bout, (float*)d_out, n);
}

// Round 3
// 1203.254 us; speedup vs baseline: 3.4365x; 1.1824x over previous
//
#include <hip/hip_runtime.h>
#include <hip/hip_fp16.h>
#include <math.h>

// GCNII forward: N=100000, E=1.6M, F_IN=300, H=64, OUT=20, L=8
// Round 3: fp16 node features (halve gather bytes), register-tiled input
// GEMM, W-in-LDS fused layer kernel with 8 gather chains.

#define HID 64
#define FIN 300
#define NOUT 20
#define ALPHA 0.1f

// ---- init: deg=1 (self loop), counts=0 --------------------------------
__global__ void init_k(float* __restrict__ deg, int* __restrict__ counts, int n) {
    int i = blockIdx.x * blockDim.x + threadIdx.x;
    if (i < n) { deg[i] = 1.0f; counts[i] = 0; }
}

__global__ void accum_k(const int* __restrict__ col, const float* __restrict__ w,
                        float* __restrict__ deg, int* __restrict__ counts, int e) {
    int i = blockIdx.x * blockDim.x + threadIdx.x;
    if (i < e) {
        int c = col[i];
        atomicAdd(&deg[c], w[i]);
        atomicAdd(&counts[c], 1);
    }
}

__global__ void dinv_k(float* __restrict__ deg, int n) {
    int i = blockIdx.x * blockDim.x + threadIdx.x;
    if (i < n) { float d = deg[i]; deg[i] = (d > 0.0f) ? rsqrtf(d) : 0.0f; }
}

// ---- scan for row_ptr --------------------------------------------------
__global__ __launch_bounds__(1024) void scan1_k(const int* __restrict__ counts,
                                                int* __restrict__ bsum, int n) {
    __shared__ int s[1024];
    int t = threadIdx.x, i = blockIdx.x * 1024 + t;
    s[t] = (i < n) ? counts[i] : 0;
    __syncthreads();
    for (int off = 512; off > 0; off >>= 1) {
        if (t < off) s[t] += s[t + off];
        __syncthreads();
    }
    if (t == 0) bsum[blockIdx.x] = s[0];
}

__global__ void scan2_k(int* __restrict__ bsum, int nb, int* __restrict__ rp,
                        int n, int e) {
    if (blockIdx.x == 0 && threadIdx.x == 0) {
        int acc = 0;
        for (int b = 0; b < nb; ++b) { int v = bsum[b]; bsum[b] = acc; acc += v; }
        rp[n] = e;
    }
}

__global__ __launch_bounds__(1024) void scan3_k(int* __restrict__ counts,
                                                const int* __restrict__ bsum,
                                                int* __restrict__ rp, int n) {
    __shared__ int s[1024];
    int t = threadIdx.x, i = blockIdx.x * 1024 + t;
    int v = (i < n) ? counts[i] : 0;
    s[t] = v;
    __syncthreads();
    for (int off = 1; off < 1024; off <<= 1) {
        int u = (t >= off) ? s[t - off] : 0;
        __syncthreads();
        s[t] += u;
        __syncthreads();
    }
    if (i < n) { rp[i] = bsum[blockIdx.x] + s[t] - v; counts[i] = 0; }
}

__global__ void fill_k(const int* __restrict__ row, const int* __restrict__ col,
                       const float* __restrict__ ew, const float* __restrict__ dinv,
                       const int* __restrict__ rp, int* __restrict__ cursor,
                       int* __restrict__ srcs, __half* __restrict__ wgt, int e) {
    int i = blockIdx.x * blockDim.x + threadIdx.x;
    if (i >= e) return;
    int c = col[i], r = row[i];
    float nw = (1.0f - ALPHA) * dinv[r] * ew[i] * dinv[c];
    int pos = rp[c] + atomicAdd(&cursor[c], 1);
    srcs[pos] = r;
    wgt[pos] = __float2half(nw);
}

// ---- input GEMM: x0h = relu(x @ W_in + b_in) as fp16 ------------------
// 128-node tile, K chunks of 60, lane computes 4 nodes x 8 cols.
#define KC 60
__global__ __launch_bounds__(256) void gemm_in_k(const float* __restrict__ x,
                                                 const float* __restrict__ Win,
                                                 const float* __restrict__ bin,
                                                 __half* __restrict__ x0h, int n) {
    __shared__ float Xs[KC][128];  // k-major transposed tile, 30.7 KB
    __shared__ float Ws[KC * 64];  // 15.4 KB
    int t = threadIdx.x, lane = t & 63, wv = t >> 6;
    int ng = lane >> 3;   // 0..7 -> node group of 4
    int cg = lane & 7;    // 0..7 -> col group of 8
    int tile = blockIdx.x * 128;
    int nl = wv * 32 + ng * 4;      // local node base (multiple of 4)
    int lrow = t & 127, lhalf = t >> 7;
    float acc[4][8];
#pragma unroll
    for (int i = 0; i < 4; ++i)
#pragma unroll
        for (int j = 0; j < 8; ++j) acc[i][j] = 0.0f;

    for (int c = 0; c < 5; ++c) {
        int kb = c * KC;
        __syncthreads();
        for (int i = t; i < KC * 64 / 4; i += 256)
            reinterpret_cast<float4*>(Ws)[i] =
                reinterpret_cast<const float4*>(Win + kb * 64)[i];
        {
            int rr = tile + lrow;
            rr = (rr < n) ? rr : (n - 1);
            const float* xp = x + (size_t)rr * FIN + kb;
            for (int kq = lhalf; kq < 15; kq += 2) {
                float4 v = *reinterpret_cast<const float4*>(xp + kq * 4);
                Xs[kq * 4 + 0][lrow] = v.x;
                Xs[kq * 4 + 1][lrow] = v.y;
                Xs[kq * 4 + 2][lrow] = v.z;
                Xs[kq * 4 + 3][lrow] = v.w;
            }
        }
        __syncthreads();
#pragma unroll 10
        for (int k = 0; k < KC; ++k) {
            float4 xv = *reinterpret_cast<const float4*>(&Xs[k][nl]);
            float4 wa = *reinterpret_cast<const float4*>(&Ws[k * 64 + cg * 8]);
            float4 wb = *reinterpret_cast<const float4*>(&Ws[k * 64 + cg * 8 + 4]);
            float xr[4] = {xv.x, xv.y, xv.z, xv.w};
            float wr[8] = {wa.x, wa.y, wa.z, wa.w, wb.x, wb.y, wb.z, wb.w};
#pragma unroll
            for (int i = 0; i < 4; ++i)
#pragma unroll
                for (int j = 0; j < 8; ++j)
                    acc[i][j] = fmaf(xr[i], wr[j], acc[i][j]);
        }
    }
    float4 ba = *reinterpret_cast<const float4*>(bin + cg * 8);
    float4 bb = *reinterpret_cast<const float4*>(bin + cg * 8 + 4);
    float br[8] = {ba.x, ba.y, ba.z, ba.w, bb.x, bb.y, bb.z, bb.w};
#pragma unroll
    for (int i = 0; i < 4; ++i) {
        int node = tile + nl + i;
        if (node >= n) break;
        union { float4 f4; __half h[8]; } u;
#pragma unroll
        for (int j = 0; j < 8; ++j)
            u.h[j] = __float2half(fmaxf(acc[i][j] + br[j], 0.0f));
        *reinterpret_cast<float4*>(x0h + (size_t)node * 64 + cg * 8) = u.f4;
    }
}

// ---- fused layer: gather(fp16) + residual + 64x64 GEMM(W in LDS) ------
__global__ __launch_bounds__(256) void layer_k(const int* __restrict__ rp,
                                               const int* __restrict__ srcs,
                                               const __half* __restrict__ wgt,
                                               const float* __restrict__ dinv,
                                               const __half* __restrict__ x0h,
                                               const __half* __restrict__ hin,
                                               __half* __restrict__ hout,
                                               const float* __restrict__ Wl,
                                               float beta, int n) {
    __shared__ float Ws[64 * 64];   // 16 KB
    __shared__ float zs[4][64];
    int t = threadIdx.x, lane = t & 63, wv = t >> 6;
    for (int i = t; i < 1024; i += 256)
        reinterpret_cast<float4*>(Ws)[i] = reinterpret_cast<const float4*>(Wl)[i];
    __syncthreads();
    int stride = gridDim.x * 4;
    for (int node = blockIdx.x * 4 + wv; node < n; node += stride) {
        size_t rowoff = (size_t)node * 64 + lane;
        float di = dinv[node];
        float z0 = fmaf(ALPHA, __half2float(x0h[rowoff]),
                        (1.0f - ALPHA) * di * di * __half2float(hin[rowoff]));
        float z1 = 0, z2 = 0, z3 = 0, z4 = 0, z5 = 0, z6 = 0, z7 = 0;
        int j = rp[node], end = rp[node + 1];
        for (; j + 8 <= end; j += 8) {
            int s0 = srcs[j],     s1 = srcs[j + 1], s2 = srcs[j + 2], s3 = srcs[j + 3];
            int s4 = srcs[j + 4], s5 = srcs[j + 5], s6 = srcs[j + 6], s7 = srcs[j + 7];
            float w0 = __half2float(wgt[j]),     w1 = __half2float(wgt[j + 1]);
            float w2 = __half2float(wgt[j + 2]), w3 = __half2float(wgt[j + 3]);
            float w4 = __half2float(wgt[j + 4]), w5 = __half2float(wgt[j + 5]);
            float w6 = __half2float(wgt[j + 6]), w7 = __half2float(wgt[j + 7]);
            z0 = fmaf(w0, __half2float(hin[(size_t)s0 * 64 + lane]), z0);
            z1 = fmaf(w1, __half2float(hin[(size_t)s1 * 64 + lane]), z1);
            z2 = fmaf(w2, __half2float(hin[(size_t)s2 * 64 + lane]), z2);
            z3 = fmaf(w3, __half2float(hin[(size_t)s3 * 64 + lane]), z3);
            z4 = fmaf(w4, __half2float(hin[(size_t)s4 * 64 + lane]), z4);
            z5 = fmaf(w5, __half2float(hin[(size_t)s5 * 64 + lane]), z5);
            z6 = fmaf(w6, __half2float(hin[(size_t)s6 * 64 + lane]), z6);
            z7 = fmaf(w7, __half2float(hin[(size_t)s7 * 64 + lane]), z7);
        }
        for (; j < end; ++j)
            z0 = fmaf(__half2float(wgt[j]),
                      __half2float(hin[(size_t)srcs[j] * 64 + lane]), z0);
        float z = ((z0 + z1) + (z2 + z3)) + ((z4 + z5) + (z6 + z7));
        zs[wv][lane] = z;
        __builtin_amdgcn_wave_barrier();
        float g0 = 0, g1 = 0, g2 = 0, g3 = 0;
#pragma unroll
        for (int q = 0; q < 16; ++q) {
            float4 zq = *reinterpret_cast<const float4*>(&zs[wv][q * 4]);
            g0 = fmaf(zq.x, Ws[(q * 4 + 0) * 64 + lane], g0);
            g1 = fmaf(zq.y, Ws[(q * 4 + 1) * 64 + lane], g1);
            g2 = fmaf(zq.z, Ws[(q * 4 + 2) * 64 + lane], g2);
            g3 = fmaf(zq.w, Ws[(q * 4 + 3) * 64 + lane], g3);
        }
        __builtin_amdgcn_wave_barrier();
        float g = (g0 + g1) + (g2 + g3);
        hout[rowoff] = __float2half(fmaxf(fmaf(beta, g, (1.0f - beta) * z), 0.0f));
    }
}

// ---- output GEMM: out = h @ W_out + b_out -----------------------------
__global__ __launch_bounds__(256) void gemm_out_k(const __half* __restrict__ h,
                                                  const float* __restrict__ Wout,
                                                  const float* __restrict__ bout,
                                                  float* __restrict__ out, int n) {
    __shared__ float hs[64][65];
    __shared__ float Ws[64 * NOUT];
    __shared__ float bs[NOUT];
    int t = threadIdx.x;
    for (int i = t; i < 64 * NOUT; i += 256) Ws[i] = Wout[i];
    if (t < NOUT) bs[t] = bout[t];
    int base = blockIdx.x * 64;
    int lim = min(64, n - base);
    for (int i = t; i < 64 * 32; i += 256) {
        int r = i >> 5, c2 = (i & 31) * 2;
        float2 v = make_float2(0.f, 0.f);
        if (r < lim) {
            __half2 hv = reinterpret_cast<const __half2*>(
                h + (size_t)(base + r) * 64)[i & 31];
            v = __half22float2(hv);
        }
        hs[r][c2] = v.x;
        hs[r][c2 + 1] = v.y;
    }
    __syncthreads();
#pragma unroll
    for (int q = 0; q < 5; ++q) {
        int of = t + 256 * q;
        int nd = of / NOUT, o = of - nd * NOUT;
        float acc = bs[o];
#pragma unroll
        for (int k = 0; k < 64; ++k) acc = fmaf(hs[nd][k], Ws[k * NOUT + o], acc);
        if (nd < lim) out[(size_t)(base + nd) * NOUT + o] = acc;
    }
}

extern "C" void kernel_launch(void* const* d_in, const int* in_sizes, int n_in,
                              void* d_out, int out_size, void* d_ws, size_t ws_size,
                              hipStream_t stream) {
    const float* x    = (const float*)d_in[0];
    const int*   ei   = (const int*)d_in[1];
    const float* ew   = (const float*)d_in[2];
    const float* Win  = (const float*)d_in[3];
    const float* bin  = (const float*)d_in[4];
    const float* cw   = (const float*)d_in[5];
    const float* Wout = (const float*)d_in[6];
    const float* bout = (const float*)d_in[7];

    const int n = in_sizes[0] / FIN;          // 100000
    const int e = in_sizes[2];                // 1600000
    const int L = in_sizes[5] / (HID * HID);  // 8
    const int* row = ei;
    const int* col = ei + e;

    size_t off = 0;
    auto alloc = [&](size_t bytes) -> char* {
        char* q = (char*)d_ws + off;
        off = (off + bytes + 255) & ~(size_t)255;
        return q;
    };
    __half* x0h  = (__half*)alloc((size_t)n * HID * 2);
    __half* hA   = (__half*)alloc((size_t)n * HID * 2);
    __half* hB   = (__half*)alloc((size_t)n * HID * 2);
    int*   srcs  = (int*)alloc((size_t)e * 4);
    __half* wgt  = (__half*)alloc((size_t)e * 2);
    float* deg   = (float*)alloc((size_t)n * 4);       // becomes dinv in place
    int*   counts= (int*)alloc((size_t)n * 4);         // becomes cursor
    int*   rp    = (int*)alloc((size_t)(n + 1) * 4);
    int*   bsum  = (int*)alloc(1024 * 4);

    const int nb = (n + 1023) / 1024;

    init_k<<<(n + 255) / 256, 256, 0, stream>>>(deg, counts, n);
    accum_k<<<(e + 255) / 256, 256, 0, stream>>>(col, ew, deg, counts, e);
    dinv_k<<<(n + 255) / 256, 256, 0, stream>>>(deg, n);
    scan1_k<<<nb, 1024, 0, stream>>>(counts, bsum, n);
    scan2_k<<<1, 1, 0, stream>>>(bsum, nb, rp, n, e);
    scan3_k<<<nb, 1024, 0, stream>>>(counts, bsum, rp, n);
    fill_k<<<(e + 255) / 256, 256, 0, stream>>>(row, col, ew, deg, rp, counts, srcs, wgt, e);

    gemm_in_k<<<(n + 127) / 128, 256, 0, stream>>>(x, Win, bin, x0h, n);

    const __half* hin = x0h;
    __half* hout = hA;
    for (int l = 0; l < L; ++l) {
        float beta = (float)log(0.5 / (double)(l + 1) + 1.0);
        layer_k<<<2048, 256, 0, stream>>>(rp, srcs, wgt, deg, x0h, hin, hout,
                                          cw + (size_t)l * HID * HID, beta, n);
        const __half* nxt = hout;
        hout = (hout == hA) ? hB : hA;
        if (l == 0) hout = (hin == x0h) ? hB : hA;  // keep x0h intact
        hin = nxt;
    }
    gemm_out_k<<<(n + 63) / 64, 256, 0, stream>>>(hin, Wout, bout, (float*)d_out, n);
}

// Round 4
// 1044.534 us; speedup vs baseline: 3.9587x; 1.1520x over previous
//
#include <hip/hip_runtime.h>
#include <hip/hip_fp16.h>
#include <math.h>

// GCNII forward: N=100000, E=1.6M, F_IN=300, H=64, OUT=20, L=8
// Round 4: packed 64-bit degree atomic, uint2 edge records, 2-edges-per-wave
// half2 gather in the fused layer kernel.

#define HID 64
#define FIN 300
#define NOUT 20
#define ALPHA 0.1f
#define FIXS 33554432.0f  // 2^25 fixed-point scale for degree

// ---- init: packed (count|deg) = 0 -------------------------------------
__global__ void init_k(unsigned long long* __restrict__ packed, int n) {
    int i = blockIdx.x * blockDim.x + threadIdx.x;
    if (i < n) packed[i] = 0ULL;
}

// ---- one 64-bit atomic per edge: count in bits 40+, fixed-point deg ---
__global__ void accum_k(const int* __restrict__ col, const float* __restrict__ w,
                        unsigned long long* __restrict__ packed, int e) {
    int i = blockIdx.x * blockDim.x + threadIdx.x;
    if (i < e) {
        unsigned q = (unsigned)__float2uint_rn(w[i] * FIXS);
        atomicAdd(&packed[col[i]], (1ULL << 40) | (unsigned long long)q);
    }
}

// ---- unpack: dinv + counts --------------------------------------------
__global__ void unpack_k(const unsigned long long* __restrict__ packed,
                         float* __restrict__ dinv, int* __restrict__ counts, int n) {
    int i = blockIdx.x * blockDim.x + threadIdx.x;
    if (i < n) {
        unsigned long long v = packed[i];
        int c = (int)(v >> 40);
        float d = 1.0f + (float)(v & 0xFFFFFFFFFFULL) * (1.0f / FIXS);  // self loop
        dinv[i] = rsqrtf(d);
        counts[i] = c;
    }
}

// ---- scan for row_ptr --------------------------------------------------
__global__ __launch_bounds__(1024) void scan1_k(const int* __restrict__ counts,
                                                int* __restrict__ bsum, int n) {
    __shared__ int s[1024];
    int t = threadIdx.x, i = blockIdx.x * 1024 + t;
    s[t] = (i < n) ? counts[i] : 0;
    __syncthreads();
    for (int off = 512; off > 0; off >>= 1) {
        if (t < off) s[t] += s[t + off];
        __syncthreads();
    }
    if (t == 0) bsum[blockIdx.x] = s[0];
}

__global__ void scan2_k(int* __restrict__ bsum, int nb, int* __restrict__ rp,
                        int n, int e) {
    if (blockIdx.x == 0 && threadIdx.x == 0) {
        int acc = 0;
        for (int b = 0; b < nb; ++b) { int v = bsum[b]; bsum[b] = acc; acc += v; }
        rp[n] = e;
    }
}

__global__ __launch_bounds__(1024) void scan3_k(int* __restrict__ counts,
                                                const int* __restrict__ bsum,
                                                int* __restrict__ rp, int n) {
    __shared__ int s[1024];
    int t = threadIdx.x, i = blockIdx.x * 1024 + t;
    int v = (i < n) ? counts[i] : 0;
    s[t] = v;
    __syncthreads();
    for (int off = 1; off < 1024; off <<= 1) {
        int u = (t >= off) ? s[t - off] : 0;
        __syncthreads();
        s[t] += u;
        __syncthreads();
    }
    if (i < n) { rp[i] = bsum[blockIdx.x] + s[t] - v; counts[i] = 0; }
}

// ---- fill CSR: one uint2 {src, float_bits(norm)} per edge -------------
__global__ void fill_k(const int* __restrict__ row, const int* __restrict__ col,
                       const float* __restrict__ ew, const float* __restrict__ dinv,
                       const int* __restrict__ rp, int* __restrict__ cursor,
                       uint2* __restrict__ edges, int e) {
    int i = blockIdx.x * blockDim.x + threadIdx.x;
    if (i >= e) return;
    int c = col[i], r = row[i];
    float nw = (1.0f - ALPHA) * dinv[r] * ew[i] * dinv[c];
    int pos = rp[c] + atomicAdd(&cursor[c], 1);
    edges[pos] = make_uint2((unsigned)r, __float_as_uint(nw));
}

// ---- input GEMM: x0h = relu(x @ W_in + b_in) as fp16 ------------------
#define KC 60
__global__ __launch_bounds__(256) void gemm_in_k(const float* __restrict__ x,
                                                 const float* __restrict__ Win,
                                                 const float* __restrict__ bin,
                                                 __half* __restrict__ x0h, int n) {
    __shared__ float Xs[KC][128];
    __shared__ float Ws[KC * 64];
    int t = threadIdx.x, lane = t & 63, wv = t >> 6;
    int ng = lane >> 3;
    int cg = lane & 7;
    int tile = blockIdx.x * 128;
    int nl = wv * 32 + ng * 4;
    int lrow = t & 127, lhalf = t >> 7;
    float acc[4][8];
#pragma unroll
    for (int i = 0; i < 4; ++i)
#pragma unroll
        for (int j = 0; j < 8; ++j) acc[i][j] = 0.0f;

    for (int c = 0; c < 5; ++c) {
        int kb = c * KC;
        __syncthreads();
        for (int i = t; i < KC * 64 / 4; i += 256)
            reinterpret_cast<float4*>(Ws)[i] =
                reinterpret_cast<const float4*>(Win + kb * 64)[i];
        {
            int rr = tile + lrow;
            rr = (rr < n) ? rr : (n - 1);
            const float* xp = x + (size_t)rr * FIN + kb;
            for (int kq = lhalf; kq < 15; kq += 2) {
                float4 v = *reinterpret_cast<const float4*>(xp + kq * 4);
                Xs[kq * 4 + 0][lrow] = v.x;
                Xs[kq * 4 + 1][lrow] = v.y;
                Xs[kq * 4 + 2][lrow] = v.z;
                Xs[kq * 4 + 3][lrow] = v.w;
            }
        }
        __syncthreads();
#pragma unroll 10
        for (int k = 0; k < KC; ++k) {
            float4 xv = *reinterpret_cast<const float4*>(&Xs[k][nl]);
            float4 wa = *reinterpret_cast<const float4*>(&Ws[k * 64 + cg * 8]);
            float4 wb = *reinterpret_cast<const float4*>(&Ws[k * 64 + cg * 8 + 4]);
            float xr[4] = {xv.x, xv.y, xv.z, xv.w};
            float wr[8] = {wa.x, wa.y, wa.z, wa.w, wb.x, wb.y, wb.z, wb.w};
#pragma unroll
            for (int i = 0; i < 4; ++i)
#pragma unroll
                for (int j = 0; j < 8; ++j)
                    acc[i][j] = fmaf(xr[i], wr[j], acc[i][j]);
        }
    }
    float4 ba = *reinterpret_cast<const float4*>(bin + cg * 8);
    float4 bb = *reinterpret_cast<const float4*>(bin + cg * 8 + 4);
    float br[8] = {ba.x, ba.y, ba.z, ba.w, bb.x, bb.y, bb.z, bb.w};
#pragma unroll
    for (int i = 0; i < 4; ++i) {
        int node = tile + nl + i;
        if (node >= n) break;
        union { float4 f4; __half h[8]; } u;
#pragma unroll
        for (int j = 0; j < 8; ++j)
            u.h[j] = __float2half(fmaxf(acc[i][j] + br[j], 0.0f));
        *reinterpret_cast<float4*>(x0h + (size_t)node * 64 + cg * 8) = u.f4;
    }
}

// ---- fused layer: 2-edge half2 gather + residual + 64x64 GEMM ---------
__global__ __launch_bounds__(256) void layer_k(const int* __restrict__ rp,
                                               const uint2* __restrict__ edges,
                                               const float* __restrict__ dinv,
                                               const __half* __restrict__ x0h,
                                               const __half* __restrict__ hin,
                                               __half* __restrict__ hout,
                                               const float* __restrict__ Wl,
                                               float beta, int n) {
    __shared__ float Ws[64 * 64];   // 16 KB
    __shared__ float zs[4][64];
    int t = threadIdx.x, lane = t & 63, wv = t >> 6;
    int hl = lane & 31, hi = lane >> 5;
    for (int i = t; i < 1024; i += 256)
        reinterpret_cast<float4*>(Ws)[i] = reinterpret_cast<const float4*>(Wl)[i];
    __syncthreads();
    const __half2* hin2 = reinterpret_cast<const __half2*>(hin);
    const __half2* x0h2 = reinterpret_cast<const __half2*>(x0h);
    int stride = gridDim.x * 4;
    for (int node = blockIdx.x * 4 + wv; node < n; node += stride) {
        int j = rp[node], end = rp[node + 1];
        float2 z0 = {0, 0}, z1 = {0, 0}, z2 = {0, 0}, z3 = {0, 0};
        for (; j + 8 <= end; j += 8) {
            int b = j + hi * 4;
            uint2 e0 = edges[b], e1 = edges[b + 1], e2 = edges[b + 2], e3 = edges[b + 3];
            float2 r0 = __half22float2(hin2[(size_t)e0.x * 32 + hl]);
            float2 r1 = __half22float2(hin2[(size_t)e1.x * 32 + hl]);
            float2 r2 = __half22float2(hin2[(size_t)e2.x * 32 + hl]);
            float2 r3 = __half22float2(hin2[(size_t)e3.x * 32 + hl]);
            float w0 = __uint_as_float(e0.y), w1 = __uint_as_float(e1.y);
            float w2 = __uint_as_float(e2.y), w3 = __uint_as_float(e3.y);
            z0.x = fmaf(w0, r0.x, z0.x); z0.y = fmaf(w0, r0.y, z0.y);
            z1.x = fmaf(w1, r1.x, z1.x); z1.y = fmaf(w1, r1.y, z1.y);
            z2.x = fmaf(w2, r2.x, z2.x); z2.y = fmaf(w2, r2.y, z2.y);
            z3.x = fmaf(w3, r3.x, z3.x); z3.y = fmaf(w3, r3.y, z3.y);
        }
        for (; j < end; j += 2) {
            int jj = j + hi;
            bool valid = jj < end;
            uint2 ee = edges[valid ? jj : j];
            float w = valid ? __uint_as_float(ee.y) : 0.0f;
            float2 r = __half22float2(hin2[(size_t)ee.x * 32 + hl]);
            z0.x = fmaf(w, r.x, z0.x); z0.y = fmaf(w, r.y, z0.y);
        }
        float2 zsum;
        zsum.x = (z0.x + z1.x) + (z2.x + z3.x);
        zsum.y = (z0.y + z1.y) + (z2.y + z3.y);
        zsum.x += __shfl_xor(zsum.x, 32);
        zsum.y += __shfl_xor(zsum.y, 32);
        // residual + self loop
        float di = dinv[node];
        float c1 = (1.0f - ALPHA) * di * di;
        float2 hr = __half22float2(hin2[(size_t)node * 32 + hl]);
        float2 x0r = __half22float2(x0h2[(size_t)node * 32 + hl]);
        zsum.x = fmaf(ALPHA, x0r.x, fmaf(c1, hr.x, zsum.x));
        zsum.y = fmaf(ALPHA, x0r.y, fmaf(c1, hr.y, zsum.y));
        if (lane < 32) reinterpret_cast<float2*>(zs[wv])[hl] = zsum;
        __builtin_amdgcn_wave_barrier();
        float g0 = 0, g1 = 0, g2 = 0, g3 = 0;
#pragma unroll
        for (int q = 0; q < 16; ++q) {
            float4 zq = *reinterpret_cast<const float4*>(&zs[wv][q * 4]);
            g0 = fmaf(zq.x, Ws[(q * 4 + 0) * 64 + lane], g0);
            g1 = fmaf(zq.y, Ws[(q * 4 + 1) * 64 + lane], g1);
            g2 = fmaf(zq.z, Ws[(q * 4 + 2) * 64 + lane], g2);
            g3 = fmaf(zq.w, Ws[(q * 4 + 3) * 64 + lane], g3);
        }
        float zmine = zs[wv][lane];
        __builtin_amdgcn_wave_barrier();
        float g = (g0 + g1) + (g2 + g3);
        hout[(size_t)node * 64 + lane] =
            __float2half(fmaxf(fmaf(beta, g, (1.0f - beta) * zmine), 0.0f));
    }
}

// ---- output GEMM: out = h @ W_out + b_out -----------------------------
__global__ __launch_bounds__(256) void gemm_out_k(const __half* __restrict__ h,
                                                  const float* __restrict__ Wout,
                                                  const float* __restrict__ bout,
                                                  float* __restrict__ out, int n) {
    __shared__ float hs[64][65];
    __shared__ float Ws[64 * NOUT];
    __shared__ float bs[NOUT];
    int t = threadIdx.x;
    for (int i = t; i < 64 * NOUT; i += 256) Ws[i] = Wout[i];
    if (t < NOUT) bs[t] = bout[t];
    int base = blockIdx.x * 64;
    int lim = min(64, n - base);
    for (int i = t; i < 64 * 32; i += 256) {
        int r = i >> 5, c2 = (i & 31) * 2;
        float2 v = make_float2(0.f, 0.f);
        if (r < lim) {
            __half2 hv = reinterpret_cast<const __half2*>(
                h + (size_t)(base + r) * 64)[i & 31];
            v = __half22float2(hv);
        }
        hs[r][c2] = v.x;
        hs[r][c2 + 1] = v.y;
    }
    __syncthreads();
#pragma unroll
    for (int q = 0; q < 5; ++q) {
        int of = t + 256 * q;
        int nd = of / NOUT, o = of - nd * NOUT;
        float acc = bs[o];
#pragma unroll
        for (int k = 0; k < 64; ++k) acc = fmaf(hs[nd][k], Ws[k * NOUT + o], acc);
        if (nd < lim) out[(size_t)(base + nd) * NOUT + o] = acc;
    }
}

extern "C" void kernel_launch(void* const* d_in, const int* in_sizes, int n_in,
                              void* d_out, int out_size, void* d_ws, size_t ws_size,
                              hipStream_t stream) {
    const float* x    = (const float*)d_in[0];
    const int*   ei   = (const int*)d_in[1];
    const float* ew   = (const float*)d_in[2];
    const float* Win  = (const float*)d_in[3];
    const float* bin  = (const float*)d_in[4];
    const float* cw   = (const float*)d_in[5];
    const float* Wout = (const float*)d_in[6];
    const float* bout = (const float*)d_in[7];

    const int n = in_sizes[0] / FIN;          // 100000
    const int e = in_sizes[2];                // 1600000
    const int L = in_sizes[5] / (HID * HID);  // 8
    const int* row = ei;
    const int* col = ei + e;

    size_t off = 0;
    auto alloc = [&](size_t bytes) -> char* {
        char* q = (char*)d_ws + off;
        off = (off + bytes + 255) & ~(size_t)255;
        return q;
    };
    __half* x0h  = (__half*)alloc((size_t)n * HID * 2);
    __half* hA   = (__half*)alloc((size_t)n * HID * 2);
    __half* hB   = (__half*)alloc((size_t)n * HID * 2);
    uint2* edges = (uint2*)alloc((size_t)e * 8);
    unsigned long long* packed = (unsigned long long*)alloc((size_t)n * 8);
    float* dinv  = (float*)alloc((size_t)n * 4);
    int*   counts= (int*)alloc((size_t)n * 4);         // becomes cursor
    int*   rp    = (int*)alloc((size_t)(n + 1) * 4);
    int*   bsum  = (int*)alloc(1024 * 4);

    const int nb = (n + 1023) / 1024;

    init_k<<<(n + 255) / 256, 256, 0, stream>>>(packed, n);
    accum_k<<<(e + 255) / 256, 256, 0, stream>>>(col, ew, packed, e);
    unpack_k<<<(n + 255) / 256, 256, 0, stream>>>(packed, dinv, counts, n);
    scan1_k<<<nb, 1024, 0, stream>>>(counts, bsum, n);
    scan2_k<<<1, 1, 0, stream>>>(bsum, nb, rp, n, e);
    scan3_k<<<nb, 1024, 0, stream>>>(counts, bsum, rp, n);
    fill_k<<<(e + 255) / 256, 256, 0, stream>>>(row, col, ew, dinv, rp, counts, edges, e);

    gemm_in_k<<<(n + 127) / 128, 256, 0, stream>>>(x, Win, bin, x0h, n);

    const __half* hin = x0h;
    __half* hout = hA;
    for (int l = 0; l < L; ++l) {
        float beta = (float)log(0.5 / (double)(l + 1) + 1.0);
        layer_k<<<2048, 256, 0, stream>>>(rp, edges, dinv, x0h, hin, hout,
                                          cw + (size_t)l * HID * HID, beta, n);
        const __half* nxt = hout;
        hout = (hout == hA) ? hB : hA;
        if (l == 0) hout = (hin == x0h) ? hB : hA;  // keep x0h intact
        hin = nxt;
    }
    gemm_out_k<<<(n + 63) / 64, 256, 0, stream>>>(hin, Wout, bout, (float*)d_out, n);
}

// Round 5
// 680.776 us; speedup vs baseline: 6.0740x; 1.5343x over previous
//
#include <hip/hip_runtime.h>
#include <hip/hip_fp16.h>
#include <math.h>

// GCNII forward: N=100000, E=1.6M, F_IN=300, H=64, OUT=20, L=8
// Round 5: split layer into (a) agg_k: 8-edges-per-wave float4 gather SpMM,
// no LDS, shfl-reduce; (b) lgemm_k: MFMA fp16 64x64 GEMM with residual+relu.

#define HID 64
#define FIN 300
#define NOUT 20
#define ALPHA 0.1f
#define FIXS 33554432.0f  // 2^25 fixed-point scale for degree

typedef _Float16 f16;
typedef f16 f16x8 __attribute__((ext_vector_type(8)));
typedef float f32x4 __attribute__((ext_vector_type(4)));

// ---- init: packed (count|deg) = 0 -------------------------------------
__global__ void init_k(unsigned long long* __restrict__ packed, int n) {
    int i = blockIdx.x * blockDim.x + threadIdx.x;
    if (i < n) packed[i] = 0ULL;
}

__global__ void accum_k(const int* __restrict__ col, const float* __restrict__ w,
                        unsigned long long* __restrict__ packed, int e) {
    int i = blockIdx.x * blockDim.x + threadIdx.x;
    if (i < e) {
        unsigned q = (unsigned)__float2uint_rn(w[i] * FIXS);
        atomicAdd(&packed[col[i]], (1ULL << 40) | (unsigned long long)q);
    }
}

__global__ void unpack_k(const unsigned long long* __restrict__ packed,
                         float* __restrict__ dinv, int* __restrict__ counts, int n) {
    int i = blockIdx.x * blockDim.x + threadIdx.x;
    if (i < n) {
        unsigned long long v = packed[i];
        int c = (int)(v >> 40);
        float d = 1.0f + (float)(v & 0xFFFFFFFFFFULL) * (1.0f / FIXS);
        dinv[i] = rsqrtf(d);
        counts[i] = c;
    }
}

// ---- scan for row_ptr --------------------------------------------------
__global__ __launch_bounds__(1024) void scan1_k(const int* __restrict__ counts,
                                                int* __restrict__ bsum, int n) {
    __shared__ int s[1024];
    int t = threadIdx.x, i = blockIdx.x * 1024 + t;
    s[t] = (i < n) ? counts[i] : 0;
    __syncthreads();
    for (int off = 512; off > 0; off >>= 1) {
        if (t < off) s[t] += s[t + off];
        __syncthreads();
    }
    if (t == 0) bsum[blockIdx.x] = s[0];
}

__global__ void scan2_k(int* __restrict__ bsum, int nb, int* __restrict__ rp,
                        int n, int e) {
    if (blockIdx.x == 0 && threadIdx.x == 0) {
        int acc = 0;
        for (int b = 0; b < nb; ++b) { int v = bsum[b]; bsum[b] = acc; acc += v; }
        rp[n] = e;
    }
}

__global__ __launch_bounds__(1024) void scan3_k(int* __restrict__ counts,
                                                const int* __restrict__ bsum,
                                                int* __restrict__ rp, int n) {
    __shared__ int s[1024];
    int t = threadIdx.x, i = blockIdx.x * 1024 + t;
    int v = (i < n) ? counts[i] : 0;
    s[t] = v;
    __syncthreads();
    for (int off = 1; off < 1024; off <<= 1) {
        int u = (t >= off) ? s[t - off] : 0;
        __syncthreads();
        s[t] += u;
        __syncthreads();
    }
    if (i < n) { rp[i] = bsum[blockIdx.x] + s[t] - v; counts[i] = 0; }
}

__global__ void fill_k(const int* __restrict__ row, const int* __restrict__ col,
                       const float* __restrict__ ew, const float* __restrict__ dinv,
                       const int* __restrict__ rp, int* __restrict__ cursor,
                       uint2* __restrict__ edges, int e) {
    int i = blockIdx.x * blockDim.x + threadIdx.x;
    if (i >= e) return;
    int c = col[i], r = row[i];
    float nw = (1.0f - ALPHA) * dinv[r] * ew[i] * dinv[c];
    int pos = rp[c] + atomicAdd(&cursor[c], 1);
    edges[pos] = make_uint2((unsigned)r, __float_as_uint(nw));
}

// ---- input GEMM: x0h = relu(x @ W_in + b_in) as fp16 ------------------
#define KC 60
__global__ __launch_bounds__(256) void gemm_in_k(const float* __restrict__ x,
                                                 const float* __restrict__ Win,
                                                 const float* __restrict__ bin,
                                                 __half* __restrict__ x0h, int n) {
    __shared__ float Xs[KC][128];
    __shared__ float Ws[KC * 64];
    int t = threadIdx.x, lane = t & 63, wv = t >> 6;
    int ng = lane >> 3;
    int cg = lane & 7;
    int tile = blockIdx.x * 128;
    int nl = wv * 32 + ng * 4;
    int lrow = t & 127, lhalf = t >> 7;
    float acc[4][8];
#pragma unroll
    for (int i = 0; i < 4; ++i)
#pragma unroll
        for (int j = 0; j < 8; ++j) acc[i][j] = 0.0f;

    for (int c = 0; c < 5; ++c) {
        int kb = c * KC;
        __syncthreads();
        for (int i = t; i < KC * 64 / 4; i += 256)
            reinterpret_cast<float4*>(Ws)[i] =
                reinterpret_cast<const float4*>(Win + kb * 64)[i];
        {
            int rr = tile + lrow;
            rr = (rr < n) ? rr : (n - 1);
            const float* xp = x + (size_t)rr * FIN + kb;
            for (int kq = lhalf; kq < 15; kq += 2) {
                float4 v = *reinterpret_cast<const float4*>(xp + kq * 4);
                Xs[kq * 4 + 0][lrow] = v.x;
                Xs[kq * 4 + 1][lrow] = v.y;
                Xs[kq * 4 + 2][lrow] = v.z;
                Xs[kq * 4 + 3][lrow] = v.w;
            }
        }
        __syncthreads();
#pragma unroll 10
        for (int k = 0; k < KC; ++k) {
            float4 xv = *reinterpret_cast<const float4*>(&Xs[k][nl]);
            float4 wa = *reinterpret_cast<const float4*>(&Ws[k * 64 + cg * 8]);
            float4 wb = *reinterpret_cast<const float4*>(&Ws[k * 64 + cg * 8 + 4]);
            float xr[4] = {xv.x, xv.y, xv.z, xv.w};
            float wr[8] = {wa.x, wa.y, wa.z, wa.w, wb.x, wb.y, wb.z, wb.w};
#pragma unroll
            for (int i = 0; i < 4; ++i)
#pragma unroll
                for (int j = 0; j < 8; ++j)
                    acc[i][j] = fmaf(xr[i], wr[j], acc[i][j]);
        }
    }
    float4 ba = *reinterpret_cast<const float4*>(bin + cg * 8);
    float4 bb = *reinterpret_cast<const float4*>(bin + cg * 8 + 4);
    float br[8] = {ba.x, ba.y, ba.z, ba.w, bb.x, bb.y, bb.z, bb.w};
#pragma unroll
    for (int i = 0; i < 4; ++i) {
        int node = tile + nl + i;
        if (node >= n) break;
        union { float4 f4; __half h[8]; } u;
#pragma unroll
        for (int j = 0; j < 8; ++j)
            u.h[j] = __float2half(fmaxf(acc[i][j] + br[j], 0.0f));
        *reinterpret_cast<float4*>(x0h + (size_t)node * 64 + cg * 8) = u.f4;
    }
}

// ---- unpack helper ------------------------------------------------------
__device__ __forceinline__ void unpack8(const float4& v, float* f) {
    const __half2* p = reinterpret_cast<const __half2*>(&v);
#pragma unroll
    for (int i = 0; i < 4; ++i) {
        float2 t = __half22float2(p[i]);
        f[2 * i] = t.x;
        f[2 * i + 1] = t.y;
    }
}

// ---- agg_k: SpMM, 8 edges per wave instruction, no LDS ----------------
__global__ __launch_bounds__(256) void agg_k(const int* __restrict__ rp,
                                             const uint2* __restrict__ edges,
                                             const float* __restrict__ dinv,
                                             const __half* __restrict__ x0h,
                                             const __half* __restrict__ hin,
                                             __half* __restrict__ z, int n) {
    int lane = threadIdx.x & 63, wv = threadIdx.x >> 6;
    int g = lane >> 3, c8 = lane & 7;
    int stride = gridDim.x * 4;
    for (int node = blockIdx.x * 4 + wv; node < n; node += stride) {
        int j = rp[node], end = rp[node + 1];
        float accA[8], accB[8];
#pragma unroll
        for (int i = 0; i < 8; ++i) { accA[i] = 0.f; accB[i] = 0.f; }
        for (; j + 16 <= end; j += 16) {
            uint2 eA = edges[j + g];
            uint2 eB = edges[j + 8 + g];
            float4 rA = ((const float4*)(hin + (size_t)eA.x * 64))[c8];
            float4 rB = ((const float4*)(hin + (size_t)eB.x * 64))[c8];
            float wA = __uint_as_float(eA.y);
            float wB = __uint_as_float(eB.y);
            float fA[8], fB[8];
            unpack8(rA, fA);
            unpack8(rB, fB);
#pragma unroll
            for (int i = 0; i < 8; ++i) {
                accA[i] = fmaf(wA, fA[i], accA[i]);
                accB[i] = fmaf(wB, fB[i], accB[i]);
            }
        }
        for (; j < end; j += 8) {
            int jj = j + g;
            uint2 ee = edges[(jj < end) ? jj : (end - 1)];
            float w = (jj < end) ? __uint_as_float(ee.y) : 0.0f;
            float4 r = ((const float4*)(hin + (size_t)ee.x * 64))[c8];
            float f[8];
            unpack8(r, f);
#pragma unroll
            for (int i = 0; i < 8; ++i) accA[i] = fmaf(w, f[i], accA[i]);
        }
#pragma unroll
        for (int i = 0; i < 8; ++i) accA[i] += accB[i];
        // reduce across the 8 edge groups (lane bits 3,4,5)
#pragma unroll
        for (int i = 0; i < 8; ++i) {
            accA[i] += __shfl_xor(accA[i], 8);
            accA[i] += __shfl_xor(accA[i], 16);
            accA[i] += __shfl_xor(accA[i], 32);
        }
        // self-loop + initial residual
        float di = dinv[node];
        float c1 = (1.0f - ALPHA) * di * di;
        float4 hs4 = ((const float4*)(hin + (size_t)node * 64))[c8];
        float4 xs4 = ((const float4*)(x0h + (size_t)node * 64))[c8];
        float hf[8], xf[8];
        unpack8(hs4, hf);
        unpack8(xs4, xf);
        union { float4 f4; __half2 h2[4]; } u;
#pragma unroll
        for (int i = 0; i < 4; ++i) {
            float v0 = fmaf(ALPHA, xf[2 * i],     fmaf(c1, hf[2 * i],     accA[2 * i]));
            float v1 = fmaf(ALPHA, xf[2 * i + 1], fmaf(c1, hf[2 * i + 1], accA[2 * i + 1]));
            u.h2[i] = __floats2half2_rn(v0, v1);
        }
        if (g == 0) ((float4*)(z + (size_t)node * 64))[c8] = u.f4;
    }
}

// ---- lgemm_k: h = relu((1-beta)*z + beta*(z @ W)), MFMA fp16 ----------
__global__ __launch_bounds__(256) void lgemm_k(const __half* __restrict__ z,
                                               const float* __restrict__ Wl,
                                               __half* __restrict__ hout,
                                               float beta, int n) {
    __shared__ f16 As[64 * 72];  // z tile, pad 8
    __shared__ f16 Bs[64 * 72];  // W^T tile, pad 8
    int t = threadIdx.x, lane = t & 63, wv = t >> 6;
    int node0 = blockIdx.x * 64;
    // stage W^T (fp32 -> fp16)
    for (int idx = t; idx < 4096; idx += 256) {
        int k = idx >> 6, c = idx & 63;
        Bs[c * 72 + k] = (f16)Wl[idx];
    }
    // stage z tile (b128 copies)
    for (int idx = t; idx < 512; idx += 256) {
        int row = idx >> 3, ch = idx & 7;
        int rr = node0 + row;
        rr = (rr < n) ? rr : (n - 1);
        float4 v = ((const float4*)(z + (size_t)rr * 64))[ch];
        *(float4*)(As + row * 72 + ch * 8) = v;
    }
    __syncthreads();
    int kg = lane >> 4;   // 0..3 k-octet group
    int lr = lane & 15;
    f16x8 a0 = *(const f16x8*)(As + (wv * 16 + lr) * 72 + kg * 8);
    f16x8 a1 = *(const f16x8*)(As + (wv * 16 + lr) * 72 + kg * 8 + 32);
    f32x4 acc0 = {0, 0, 0, 0}, acc1 = {0, 0, 0, 0}, acc2 = {0, 0, 0, 0}, acc3 = {0, 0, 0, 0};
    {
        f16x8 b0 = *(const f16x8*)(Bs + (0 * 16 + lr) * 72 + kg * 8);
        f16x8 b1 = *(const f16x8*)(Bs + (0 * 16 + lr) * 72 + kg * 8 + 32);
        acc0 = __builtin_amdgcn_mfma_f32_16x16x32_f16(a0, b0, acc0, 0, 0, 0);
        acc0 = __builtin_amdgcn_mfma_f32_16x16x32_f16(a1, b1, acc0, 0, 0, 0);
    }
    {
        f16x8 b0 = *(const f16x8*)(Bs + (1 * 16 + lr) * 72 + kg * 8);
        f16x8 b1 = *(const f16x8*)(Bs + (1 * 16 + lr) * 72 + kg * 8 + 32);
        acc1 = __builtin_amdgcn_mfma_f32_16x16x32_f16(a0, b0, acc1, 0, 0, 0);
        acc1 = __builtin_amdgcn_mfma_f32_16x16x32_f16(a1, b1, acc1, 0, 0, 0);
    }
    {
        f16x8 b0 = *(const f16x8*)(Bs + (2 * 16 + lr) * 72 + kg * 8);
        f16x8 b1 = *(const f16x8*)(Bs + (2 * 16 + lr) * 72 + kg * 8 + 32);
        acc2 = __builtin_amdgcn_mfma_f32_16x16x32_f16(a0, b0, acc2, 0, 0, 0);
        acc2 = __builtin_amdgcn_mfma_f32_16x16x32_f16(a1, b1, acc2, 0, 0, 0);
    }
    {
        f16x8 b0 = *(const f16x8*)(Bs + (3 * 16 + lr) * 72 + kg * 8);
        f16x8 b1 = *(const f16x8*)(Bs + (3 * 16 + lr) * 72 + kg * 8 + 32);
        acc3 = __builtin_amdgcn_mfma_f32_16x16x32_f16(a0, b0, acc3, 0, 0, 0);
        acc3 = __builtin_amdgcn_mfma_f32_16x16x32_f16(a1, b1, acc3, 0, 0, 0);
    }
    // epilogue: D row = (lane>>4)*4 + reg, col = lane&15 (guide-verified)
    float omb = 1.0f - beta;
#pragma unroll
    for (int nt = 0; nt < 4; ++nt) {
        f32x4 acc = (nt == 0) ? acc0 : (nt == 1) ? acc1 : (nt == 2) ? acc2 : acc3;
        int col = nt * 16 + lr;
#pragma unroll
        for (int r = 0; r < 4; ++r) {
            int lrow = wv * 16 + kg * 4 + r;
            int node = node0 + lrow;
            if (node < n) {
                float zv = (float)As[lrow * 72 + col];
                float o = fmaxf(fmaf(beta, acc[r], omb * zv), 0.0f);
                hout[(size_t)node * 64 + col] = __float2half(o);
            }
        }
    }
}

// ---- output GEMM: out = h @ W_out + b_out -----------------------------
__global__ __launch_bounds__(256) void gemm_out_k(const __half* __restrict__ h,
                                                  const float* __restrict__ Wout,
                                                  const float* __restrict__ bout,
                                                  float* __restrict__ out, int n) {
    __shared__ float hs[64][65];
    __shared__ float Ws[64 * NOUT];
    __shared__ float bs[NOUT];
    int t = threadIdx.x;
    for (int i = t; i < 64 * NOUT; i += 256) Ws[i] = Wout[i];
    if (t < NOUT) bs[t] = bout[t];
    int base = blockIdx.x * 64;
    int lim = min(64, n - base);
    for (int i = t; i < 64 * 32; i += 256) {
        int r = i >> 5, c2 = (i & 31) * 2;
        float2 v = make_float2(0.f, 0.f);
        if (r < lim) {
            __half2 hv = reinterpret_cast<const __half2*>(
                h + (size_t)(base + r) * 64)[i & 31];
            v = __half22float2(hv);
        }
        hs[r][c2] = v.x;
        hs[r][c2 + 1] = v.y;
    }
    __syncthreads();
#pragma unroll
    for (int q = 0; q < 5; ++q) {
        int of = t + 256 * q;
        int nd = of / NOUT, o = of - nd * NOUT;
        float acc = bs[o];
#pragma unroll
        for (int k = 0; k < 64; ++k) acc = fmaf(hs[nd][k], Ws[k * NOUT + o], acc);
        if (nd < lim) out[(size_t)(base + nd) * NOUT + o] = acc;
    }
}

extern "C" void kernel_launch(void* const* d_in, const int* in_sizes, int n_in,
                              void* d_out, int out_size, void* d_ws, size_t ws_size,
                              hipStream_t stream) {
    const float* x    = (const float*)d_in[0];
    const int*   ei   = (const int*)d_in[1];
    const float* ew   = (const float*)d_in[2];
    const float* Win  = (const float*)d_in[3];
    const float* bin  = (const float*)d_in[4];
    const float* cw   = (const float*)d_in[5];
    const float* Wout = (const float*)d_in[6];
    const float* bout = (const float*)d_in[7];

    const int n = in_sizes[0] / FIN;          // 100000
    const int e = in_sizes[2];                // 1600000
    const int L = in_sizes[5] / (HID * HID);  // 8
    const int* row = ei;
    const int* col = ei + e;

    size_t off = 0;
    auto alloc = [&](size_t bytes) -> char* {
        char* q = (char*)d_ws + off;
        off = (off + bytes + 255) & ~(size_t)255;
        return q;
    };
    __half* x0h  = (__half*)alloc((size_t)n * HID * 2);
    __half* hA   = (__half*)alloc((size_t)n * HID * 2);
    __half* zb   = (__half*)alloc((size_t)n * HID * 2);
    uint2* edges = (uint2*)alloc((size_t)e * 8);
    unsigned long long* packed = (unsigned long long*)alloc((size_t)n * 8);
    float* dinv  = (float*)alloc((size_t)n * 4);
    int*   counts= (int*)alloc((size_t)n * 4);         // becomes cursor
    int*   rp    = (int*)alloc((size_t)(n + 1) * 4);
    int*   bsum  = (int*)alloc(1024 * 4);

    const int nb = (n + 1023) / 1024;

    init_k<<<(n + 255) / 256, 256, 0, stream>>>(packed, n);
    accum_k<<<(e + 255) / 256, 256, 0, stream>>>(col, ew, packed, e);
    unpack_k<<<(n + 255) / 256, 256, 0, stream>>>(packed, dinv, counts, n);
    scan1_k<<<nb, 1024, 0, stream>>>(counts, bsum, n);
    scan2_k<<<1, 1, 0, stream>>>(bsum, nb, rp, n, e);
    scan3_k<<<nb, 1024, 0, stream>>>(counts, bsum, rp, n);
    fill_k<<<(e + 255) / 256, 256, 0, stream>>>(row, col, ew, dinv, rp, counts, edges, e);

    gemm_in_k<<<(n + 127) / 128, 256, 0, stream>>>(x, Win, bin, x0h, n);

    const int ngemm = (n + 63) / 64;
    const __half* hin = x0h;
    for (int l = 0; l < L; ++l) {
        float beta = (float)log(0.5 / (double)(l + 1) + 1.0);
        agg_k<<<2048, 256, 0, stream>>>(rp, edges, dinv, x0h, hin, zb, n);
        lgemm_k<<<ngemm, 256, 0, stream>>>(zb, cw + (size_t)l * HID * HID, hA, beta, n);
        hin = hA;
    }
    gemm_out_k<<<(n + 63) / 64, 256, 0, stream>>>(hin, Wout, bout, (float*)d_out, n);
}

// Round 6
// 536.443 us; speedup vs baseline: 7.7083x; 1.2691x over previous
//
#include <hip/hip_runtime.h>
#include <hip/hip_fp16.h>
#include <math.h>

// GCNII forward: N=100000, E=1.6M, F_IN=300, H=64, OUT=20, L=8
// Round 6: MFMA input GEMM (fp16, validated fragment layout), fused
// layer kernel (group-per-node gather -> LDS z -> MFMA 64x64 + residual),
// 4-byte packed edge records.

#define HID 64
#define FIN 300
#define NOUT 20
#define ALPHA 0.1f
#define FIXS 33554432.0f  // 2^25 fixed-point scale for degree

typedef _Float16 f16;
typedef f16 f16x8 __attribute__((ext_vector_type(8)));
typedef float f32x4 __attribute__((ext_vector_type(4)));

// ---- helpers -----------------------------------------------------------
__device__ __forceinline__ float wdec(unsigned v) {
    union { unsigned short u; __half h; } c;
    c.u = (unsigned short)(v >> 17);
    return __half2float(c.h);
}

__device__ __forceinline__ void unpack8(const float4& v, float* f) {
    const __half2* p = reinterpret_cast<const __half2*>(&v);
#pragma unroll
    for (int i = 0; i < 4; ++i) {
        float2 t = __half22float2(p[i]);
        f[2 * i] = t.x;
        f[2 * i + 1] = t.y;
    }
}

// ---- init: packed (count|deg) = 0 -------------------------------------
__global__ void init_k(unsigned long long* __restrict__ packed, int n) {
    int i = blockIdx.x * blockDim.x + threadIdx.x;
    if (i < n) packed[i] = 0ULL;
}

__global__ void accum_k(const int* __restrict__ col, const float* __restrict__ w,
                        unsigned long long* __restrict__ packed, int e) {
    int i = blockIdx.x * blockDim.x + threadIdx.x;
    if (i < e) {
        unsigned q = (unsigned)__float2uint_rn(w[i] * FIXS);
        atomicAdd(&packed[col[i]], (1ULL << 40) | (unsigned long long)q);
    }
}

__global__ void unpack_k(const unsigned long long* __restrict__ packed,
                         float* __restrict__ dinv, int* __restrict__ counts, int n) {
    int i = blockIdx.x * blockDim.x + threadIdx.x;
    if (i < n) {
        unsigned long long v = packed[i];
        int c = (int)(v >> 40);
        float d = 1.0f + (float)(v & 0xFFFFFFFFFFULL) * (1.0f / FIXS);
        dinv[i] = rsqrtf(d);
        counts[i] = c;
    }
}

// ---- scan for row_ptr --------------------------------------------------
__global__ __launch_bounds__(1024) void scan1_k(const int* __restrict__ counts,
                                                int* __restrict__ bsum, int n) {
    __shared__ int s[1024];
    int t = threadIdx.x, i = blockIdx.x * 1024 + t;
    s[t] = (i < n) ? counts[i] : 0;
    __syncthreads();
    for (int off = 512; off > 0; off >>= 1) {
        if (t < off) s[t] += s[t + off];
        __syncthreads();
    }
    if (t == 0) bsum[blockIdx.x] = s[0];
}

__global__ void scan2_k(int* __restrict__ bsum, int nb, int* __restrict__ rp,
                        int n, int e) {
    if (blockIdx.x == 0 && threadIdx.x == 0) {
        int acc = 0;
        for (int b = 0; b < nb; ++b) { int v = bsum[b]; bsum[b] = acc; acc += v; }
        rp[n] = e;
    }
}

__global__ __launch_bounds__(1024) void scan3_k(int* __restrict__ counts,
                                                const int* __restrict__ bsum,
                                                int* __restrict__ rp, int n) {
    __shared__ int s[1024];
    int t = threadIdx.x, i = blockIdx.x * 1024 + t;
    int v = (i < n) ? counts[i] : 0;
    s[t] = v;
    __syncthreads();
    for (int off = 1; off < 1024; off <<= 1) {
        int u = (t >= off) ? s[t - off] : 0;
        __syncthreads();
        s[t] += u;
        __syncthreads();
    }
    if (i < n) { rp[i] = bsum[blockIdx.x] + s[t] - v; counts[i] = 0; }
}

// ---- fill CSR: packed uint32 {fp16 weight[15] | src[17]} --------------
__global__ void fill_k(const int* __restrict__ row, const int* __restrict__ col,
                       const float* __restrict__ ew, const float* __restrict__ dinv,
                       const int* __restrict__ rp, int* __restrict__ cursor,
                       unsigned* __restrict__ edges, int e) {
    int i = blockIdx.x * blockDim.x + threadIdx.x;
    if (i >= e) return;
    int c = col[i], r = row[i];
    float nw = (1.0f - ALPHA) * dinv[r] * ew[i] * dinv[c];
    union { __half h; unsigned short u; } cv;
    cv.h = __float2half(nw);  // nw >= 0 -> bit15 == 0
    int pos = rp[c] + atomicAdd(&cursor[c], 1);
    edges[pos] = ((unsigned)cv.u << 17) | (unsigned)r;
}

// ---- W^T fp16 precompute for input GEMM (padded K=320) ----------------
__global__ void wt_k(const float* __restrict__ Win, f16* __restrict__ Wt) {
    int i = blockIdx.x * blockDim.x + threadIdx.x;  // 64*320
    if (i < 64 * 320) {
        int c = i / 320, k = i - c * 320;
        Wt[i] = (k < FIN) ? (f16)Win[k * 64 + c] : (f16)0.0f;
    }
}

// ---- input GEMM: x0h = relu(x @ W_in + b_in) via MFMA fp16 ------------
__global__ __launch_bounds__(256) void gemm_in_k(const float* __restrict__ x,
                                                 const f16* __restrict__ Wt,
                                                 const float* __restrict__ bin,
                                                 __half* __restrict__ x0h, int n) {
    __shared__ f16 As[64 * 72];  // x chunk tile (64 nodes x 64 k), pad 8
    int t = threadIdx.x, lane = t & 63, wv = t >> 6;
    int node0 = blockIdx.x * 64;
    int lr = lane & 15, kg = lane >> 4;
    f32x4 acc0 = {0, 0, 0, 0}, acc1 = {0, 0, 0, 0}, acc2 = {0, 0, 0, 0}, acc3 = {0, 0, 0, 0};
    int fi = t & 15;
    for (int c = 0; c < 5; ++c) {
        __syncthreads();
        // stage 64 x 64 fp32 chunk -> fp16 LDS (coalesced 256B/row by 16 lanes)
#pragma unroll
        for (int it = 0; it < 4; ++it) {
            int row = (t >> 4) + it * 16;
            int rr = node0 + row;
            rr = (rr < n) ? rr : (n - 1);
            int kbase = c * 64 + fi * 4;
            float4 v = make_float4(0.f, 0.f, 0.f, 0.f);
            if (kbase < FIN)
                v = *reinterpret_cast<const float4*>(x + (size_t)rr * FIN + kbase);
            union { float2 f2; f16 h[4]; } u;
            u.h[0] = (f16)v.x; u.h[1] = (f16)v.y; u.h[2] = (f16)v.z; u.h[3] = (f16)v.w;
            *reinterpret_cast<float2*>(As + row * 72 + fi * 4) = u.f2;
        }
        __syncthreads();
#pragma unroll
        for (int ks = 0; ks < 2; ++ks) {
            f16x8 a = *(const f16x8*)(As + (wv * 16 + lr) * 72 + ks * 32 + kg * 8);
            const f16* wb = Wt + c * 64 + ks * 32 + kg * 8;
            f16x8 b0 = *(const f16x8*)(wb + (0 * 16 + lr) * 320);
            f16x8 b1 = *(const f16x8*)(wb + (1 * 16 + lr) * 320);
            f16x8 b2 = *(const f16x8*)(wb + (2 * 16 + lr) * 320);
            f16x8 b3 = *(const f16x8*)(wb + (3 * 16 + lr) * 320);
            acc0 = __builtin_amdgcn_mfma_f32_16x16x32_f16(a, b0, acc0, 0, 0, 0);
            acc1 = __builtin_amdgcn_mfma_f32_16x16x32_f16(a, b1, acc1, 0, 0, 0);
            acc2 = __builtin_amdgcn_mfma_f32_16x16x32_f16(a, b2, acc2, 0, 0, 0);
            acc3 = __builtin_amdgcn_mfma_f32_16x16x32_f16(a, b3, acc3, 0, 0, 0);
        }
    }
    // epilogue: bias + relu -> As (fp16), then coalesced stores
    float bi0 = bin[0 * 16 + lr], bi1 = bin[1 * 16 + lr];
    float bi2 = bin[2 * 16 + lr], bi3 = bin[3 * 16 + lr];
    f16 ov[4][4];
#pragma unroll
    for (int r = 0; r < 4; ++r) {
        ov[0][r] = (f16)fmaxf(acc0[r] + bi0, 0.f);
        ov[1][r] = (f16)fmaxf(acc1[r] + bi1, 0.f);
        ov[2][r] = (f16)fmaxf(acc2[r] + bi2, 0.f);
        ov[3][r] = (f16)fmaxf(acc3[r] + bi3, 0.f);
    }
    __syncthreads();
#pragma unroll
    for (int cg = 0; cg < 4; ++cg)
#pragma unroll
        for (int r = 0; r < 4; ++r)
            As[(wv * 16 + kg * 4 + r) * 72 + cg * 16 + lr] = ov[cg][r];
    __syncthreads();
#pragma unroll
    for (int it = 0; it < 2; ++it) {
        int idx = t + it * 256;
        int row = idx >> 3, ch = idx & 7;
        int node = node0 + row;
        if (node < n)
            ((float4*)(x0h + (size_t)node * 64))[ch] =
                *reinterpret_cast<const float4*>(As + row * 72 + ch * 8);
    }
}

// ---- fused layer: group-per-node gather -> LDS z -> MFMA + residual ----
__global__ __launch_bounds__(256) void layer_k(const int* __restrict__ rp,
                                               const unsigned* __restrict__ edges,
                                               const float* __restrict__ dinv,
                                               const __half* __restrict__ x0h,
                                               const __half* __restrict__ hin,
                                               __half* __restrict__ hout,
                                               const float* __restrict__ Wl,
                                               float beta, int n) {
    __shared__ f16 As[64 * 72];  // z tile
    __shared__ f16 Bs[64 * 72];  // W^T tile
    int t = threadIdx.x, lane = t & 63, wv = t >> 6;
    int node0 = blockIdx.x * 64;
    // stage W^T fp16
    for (int i = t; i < 4096; i += 256) {
        int k = i >> 6, c = i & 63;
        Bs[c * 72 + k] = (f16)Wl[i];
    }
    int g = lane >> 3, c8 = lane & 7;
#pragma unroll
    for (int pass = 0; pass < 2; ++pass) {
        int row = pass * 32 + wv * 8 + g;
        int node = node0 + row;
        int nd = (node < n) ? node : (n - 1);
        int j = rp[nd], end = (node < n) ? rp[nd + 1] : j;
        float a0[8], a1[8];
#pragma unroll
        for (int i = 0; i < 8; ++i) { a0[i] = 0.f; a1[i] = 0.f; }
        while (__any(j < end)) {
            bool v0 = j < end, v1 = (j + 1) < end;
            unsigned e0 = edges[v0 ? j : 0];
            unsigned e1 = edges[v1 ? (j + 1) : 0];
            float w0 = v0 ? wdec(e0) : 0.f;
            float w1 = v1 ? wdec(e1) : 0.f;
            float4 r0 = ((const float4*)(hin + (size_t)(e0 & 0x1FFFF) * 64))[c8];
            float4 r1 = ((const float4*)(hin + (size_t)(e1 & 0x1FFFF) * 64))[c8];
            float f0[8], f1[8];
            unpack8(r0, f0);
            unpack8(r1, f1);
#pragma unroll
            for (int i = 0; i < 8; ++i) {
                a0[i] = fmaf(w0, f0[i], a0[i]);
                a1[i] = fmaf(w1, f1[i], a1[i]);
            }
            j += 2;
        }
        float di = dinv[nd];
        float c1 = (1.0f - ALPHA) * di * di;
        float4 hs4 = ((const float4*)(hin + (size_t)nd * 64))[c8];
        float4 xs4 = ((const float4*)(x0h + (size_t)nd * 64))[c8];
        float hf[8], xf[8];
        unpack8(hs4, hf);
        unpack8(xs4, xf);
        f16x8 zv8;
#pragma unroll
        for (int i = 0; i < 8; ++i)
            zv8[i] = (f16)fmaf(ALPHA, xf[i], fmaf(c1, hf[i], a0[i] + a1[i]));
        *(f16x8*)(As + row * 72 + c8 * 8) = zv8;
    }
    __syncthreads();
    // MFMA: h = relu((1-beta)*z + beta*(z @ W))
    int lr = lane & 15, kg = lane >> 4;
    f32x4 acc0 = {0, 0, 0, 0}, acc1 = {0, 0, 0, 0}, acc2 = {0, 0, 0, 0}, acc3 = {0, 0, 0, 0};
    f16x8 af0 = *(const f16x8*)(As + (wv * 16 + lr) * 72 + kg * 8);
    f16x8 af1 = *(const f16x8*)(As + (wv * 16 + lr) * 72 + 32 + kg * 8);
    {
        f16x8 b0 = *(const f16x8*)(Bs + (0 * 16 + lr) * 72 + kg * 8);
        f16x8 b1 = *(const f16x8*)(Bs + (0 * 16 + lr) * 72 + 32 + kg * 8);
        acc0 = __builtin_amdgcn_mfma_f32_16x16x32_f16(af0, b0, acc0, 0, 0, 0);
        acc0 = __builtin_amdgcn_mfma_f32_16x16x32_f16(af1, b1, acc0, 0, 0, 0);
    }
    {
        f16x8 b0 = *(const f16x8*)(Bs + (1 * 16 + lr) * 72 + kg * 8);
        f16x8 b1 = *(const f16x8*)(Bs + (1 * 16 + lr) * 72 + 32 + kg * 8);
        acc1 = __builtin_amdgcn_mfma_f32_16x16x32_f16(af0, b0, acc1, 0, 0, 0);
        acc1 = __builtin_amdgcn_mfma_f32_16x16x32_f16(af1, b1, acc1, 0, 0, 0);
    }
    {
        f16x8 b0 = *(const f16x8*)(Bs + (2 * 16 + lr) * 72 + kg * 8);
        f16x8 b1 = *(const f16x8*)(Bs + (2 * 16 + lr) * 72 + 32 + kg * 8);
        acc2 = __builtin_amdgcn_mfma_f32_16x16x32_f16(af0, b0, acc2, 0, 0, 0);
        acc2 = __builtin_amdgcn_mfma_f32_16x16x32_f16(af1, b1, acc2, 0, 0, 0);
    }
    {
        f16x8 b0 = *(const f16x8*)(Bs + (3 * 16 + lr) * 72 + kg * 8);
        f16x8 b1 = *(const f16x8*)(Bs + (3 * 16 + lr) * 72 + 32 + kg * 8);
        acc3 = __builtin_amdgcn_mfma_f32_16x16x32_f16(af0, b0, acc3, 0, 0, 0);
        acc3 = __builtin_amdgcn_mfma_f32_16x16x32_f16(af1, b1, acc3, 0, 0, 0);
    }
    float omb = 1.0f - beta;
    f16 ov[4][4];
#pragma unroll
    for (int cg = 0; cg < 4; ++cg) {
        f32x4 acc = (cg == 0) ? acc0 : (cg == 1) ? acc1 : (cg == 2) ? acc2 : acc3;
        int col = cg * 16 + lr;
#pragma unroll
        for (int r = 0; r < 4; ++r) {
            float zv = (float)As[(wv * 16 + kg * 4 + r) * 72 + col];
            ov[cg][r] = (f16)fmaxf(fmaf(beta, acc[r], omb * zv), 0.f);
        }
    }
    __syncthreads();
#pragma unroll
    for (int cg = 0; cg < 4; ++cg)
#pragma unroll
        for (int r = 0; r < 4; ++r)
            As[(wv * 16 + kg * 4 + r) * 72 + cg * 16 + lr] = ov[cg][r];
    __syncthreads();
#pragma unroll
    for (int it = 0; it < 2; ++it) {
        int idx = t + it * 256;
        int row = idx >> 3, ch = idx & 7;
        int node = node0 + row;
        if (node < n)
            ((float4*)(hout + (size_t)node * 64))[ch] =
                *reinterpret_cast<const float4*>(As + row * 72 + ch * 8);
    }
}

// ---- output GEMM: out = h @ W_out + b_out -----------------------------
__global__ __launch_bounds__(256) void gemm_out_k(const __half* __restrict__ h,
                                                  const float* __restrict__ Wout,
                                                  const float* __restrict__ bout,
                                                  float* __restrict__ out, int n) {
    __shared__ float hs[64][65];
    __shared__ float Ws[64 * NOUT];
    __shared__ float bs[NOUT];
    int t = threadIdx.x;
    for (int i = t; i < 64 * NOUT; i += 256) Ws[i] = Wout[i];
    if (t < NOUT) bs[t] = bout[t];
    int base = blockIdx.x * 64;
    int lim = min(64, n - base);
    for (int i = t; i < 64 * 32; i += 256) {
        int r = i >> 5, c2 = (i & 31) * 2;
        float2 v = make_float2(0.f, 0.f);
        if (r < lim) {
            __half2 hv = reinterpret_cast<const __half2*>(
                h + (size_t)(base + r) * 64)[i & 31];
            v = __half22float2(hv);
        }
        hs[r][c2] = v.x;
        hs[r][c2 + 1] = v.y;
    }
    __syncthreads();
#pragma unroll
    for (int q = 0; q < 5; ++q) {
        int of = t + 256 * q;
        int nd = of / NOUT, o = of - nd * NOUT;
        float acc = bs[o];
#pragma unroll
        for (int k = 0; k < 64; ++k) acc = fmaf(hs[nd][k], Ws[k * NOUT + o], acc);
        if (nd < lim) out[(size_t)(base + nd) * NOUT + o] = acc;
    }
}

extern "C" void kernel_launch(void* const* d_in, const int* in_sizes, int n_in,
                              void* d_out, int out_size, void* d_ws, size_t ws_size,
                              hipStream_t stream) {
    const float* x    = (const float*)d_in[0];
    const int*   ei   = (const int*)d_in[1];
    const float* ew   = (const float*)d_in[2];
    const float* Win  = (const float*)d_in[3];
    const float* bin  = (const float*)d_in[4];
    const float* cw   = (const float*)d_in[5];
    const float* Wout = (const float*)d_in[6];
    const float* bout = (const float*)d_in[7];

    const int n = in_sizes[0] / FIN;          // 100000
    const int e = in_sizes[2];                // 1600000
    const int L = in_sizes[5] / (HID * HID);  // 8
    const int* row = ei;
    const int* col = ei + e;

    size_t off = 0;
    auto alloc = [&](size_t bytes) -> char* {
        char* q = (char*)d_ws + off;
        off = (off + bytes + 255) & ~(size_t)255;
        return q;
    };
    __half* x0h  = (__half*)alloc((size_t)n * HID * 2);
    __half* hA   = (__half*)alloc((size_t)n * HID * 2);
    __half* hB   = (__half*)alloc((size_t)n * HID * 2);
    unsigned* edges = (unsigned*)alloc((size_t)e * 4);
    unsigned long long* packed = (unsigned long long*)alloc((size_t)n * 8);
    float* dinv  = (float*)alloc((size_t)n * 4);
    int*   counts= (int*)alloc((size_t)n * 4);         // becomes cursor
    int*   rp    = (int*)alloc((size_t)(n + 1) * 4);
    int*   bsum  = (int*)alloc(1024 * 4);
    f16*   Wt    = (f16*)alloc((size_t)64 * 320 * 2);

    const int nb = (n + 1023) / 1024;
    const int ntile = (n + 63) / 64;

    init_k<<<(n + 255) / 256, 256, 0, stream>>>(packed, n);
    accum_k<<<(e + 255) / 256, 256, 0, stream>>>(col, ew, packed, e);
    unpack_k<<<(n + 255) / 256, 256, 0, stream>>>(packed, dinv, counts, n);
    scan1_k<<<nb, 1024, 0, stream>>>(counts, bsum, n);
    scan2_k<<<1, 1, 0, stream>>>(bsum, nb, rp, n, e);
    scan3_k<<<nb, 1024, 0, stream>>>(counts, bsum, rp, n);
    fill_k<<<(e + 255) / 256, 256, 0, stream>>>(row, col, ew, dinv, rp, counts, edges, e);

    wt_k<<<(64 * 320 + 255) / 256, 256, 0, stream>>>(Win, Wt);
    gemm_in_k<<<ntile, 256, 0, stream>>>(x, Wt, bin, x0h, n);

    const __half* hin = x0h;
    __half* hout = hA;
    for (int l = 0; l < L; ++l) {
        float beta = (float)log(0.5 / (double)(l + 1) + 1.0);
        layer_k<<<ntile, 256, 0, stream>>>(rp, edges, dinv, x0h, hin, hout,
                                           cw + (size_t)l * HID * HID, beta, n);
        hin = hout;
        hout = (hout == hA) ? hB : hA;
    }
    gemm_out_k<<<(n + 63) / 64, 256, 0, stream>>>(hin, Wout, bout, (float*)d_out, n);
}

// Round 7
// 498.554 us; speedup vs baseline: 8.2941x; 1.0760x over previous
//
#include <hip/hip_runtime.h>
#include <hip/hip_fp16.h>
#include <math.h>

// GCNII forward: N=100000, E=1.6M, F_IN=300, H=64, OUT=20, L=8
// Round 7: rank-trick CSR build (no cursor atomics), 32-bit packed degree
// atomic, XCD-binned fill for write locality. Compute kernels unchanged.

#define HID 64
#define FIN 300
#define NOUT 20
#define ALPHA 0.1f
#define DSCALE 262144.0f   // 2^18 fixed-point scale for weighted degree
#define CNT_SHIFT 25
#define DEG_MASK 0x1FFFFFFu

typedef _Float16 f16;
typedef f16 f16x8 __attribute__((ext_vector_type(8)));
typedef float f32x4 __attribute__((ext_vector_type(4)));

// ---- helpers -----------------------------------------------------------
__device__ __forceinline__ float wdec(unsigned v) {
    union { unsigned short u; __half h; } c;
    c.u = (unsigned short)(v >> 17);
    return __half2float(c.h);
}

__device__ __forceinline__ void unpack8(const float4& v, float* f) {
    const __half2* p = reinterpret_cast<const __half2*>(&v);
#pragma unroll
    for (int i = 0; i < 4; ++i) {
        float2 t = __half22float2(p[i]);
        f[2 * i] = t.x;
        f[2 * i + 1] = t.y;
    }
}

// ---- init: packed (count|deg) = 0 -------------------------------------
__global__ void init_k(unsigned* __restrict__ packed, int n) {
    int i = blockIdx.x * blockDim.x + threadIdx.x;
    if (i < n) packed[i] = 0u;
}

// ---- one 32-bit atomic per edge; returned old value gives edge rank ----
__global__ void accum_k(const int* __restrict__ col, const float* __restrict__ w,
                        unsigned* __restrict__ packed,
                        unsigned char* __restrict__ rank, int e) {
    int i = blockIdx.x * blockDim.x + threadIdx.x;
    if (i < e) {
        unsigned q = (unsigned)__float2uint_rn(w[i] * DSCALE);
        unsigned old = atomicAdd(&packed[col[i]], (1u << CNT_SHIFT) | q);
        rank[i] = (unsigned char)(old >> CNT_SHIFT);
    }
}

// ---- fused unpack (dinv) + per-block count sums ------------------------
__global__ __launch_bounds__(1024) void unpackscan_k(const unsigned* __restrict__ packed,
                                                     float* __restrict__ dinv,
                                                     int* __restrict__ bsum, int n) {
    __shared__ int s[1024];
    int t = threadIdx.x, i = blockIdx.x * 1024 + t;
    int cnt = 0;
    if (i < n) {
        unsigned v = packed[i];
        cnt = (int)(v >> CNT_SHIFT);
        float d = 1.0f + (float)(v & DEG_MASK) * (1.0f / DSCALE);
        dinv[i] = rsqrtf(d);
    }
    s[t] = cnt;
    __syncthreads();
    for (int off = 512; off > 0; off >>= 1) {
        if (t < off) s[t] += s[t + off];
        __syncthreads();
    }
    if (t == 0) bsum[blockIdx.x] = s[0];
}

__global__ void scan2_k(int* __restrict__ bsum, int nb, int* __restrict__ rp,
                        int n, int e) {
    if (blockIdx.x == 0 && threadIdx.x == 0) {
        int acc = 0;
        for (int b = 0; b < nb; ++b) { int v = bsum[b]; bsum[b] = acc; acc += v; }
        rp[n] = e;
    }
}

__global__ __launch_bounds__(1024) void scan3_k(const unsigned* __restrict__ packed,
                                                const int* __restrict__ bsum,
                                                int* __restrict__ rp, int n) {
    __shared__ int s[1024];
    int t = threadIdx.x, i = blockIdx.x * 1024 + t;
    int v = (i < n) ? (int)(packed[i] >> CNT_SHIFT) : 0;
    s[t] = v;
    __syncthreads();
    for (int off = 1; off < 1024; off <<= 1) {
        int u = (t >= off) ? s[t - off] : 0;
        __syncthreads();
        s[t] += u;
        __syncthreads();
    }
    if (i < n) rp[i] = bsum[blockIdx.x] + s[t] - v;
}

// ---- fill CSR: XCD-binned by destination range, no atomics ------------
__global__ __launch_bounds__(256) void fill_k(const int* __restrict__ row,
                                              const int* __restrict__ col,
                                              const float* __restrict__ ew,
                                              const float* __restrict__ dinv,
                                              const int* __restrict__ rp,
                                              const unsigned char* __restrict__ rank,
                                              unsigned* __restrict__ edges,
                                              int e, int n) {
    int xcd = blockIdx.x & 7;
    int lo = (int)(((long long)n * xcd) >> 3);
    int hi = (int)(((long long)n * (xcd + 1)) >> 3);
    int nblk = gridDim.x >> 3;
    int stride = nblk * 256;
    for (int i = (blockIdx.x >> 3) * 256 + threadIdx.x; i < e; i += stride) {
        int c = col[i];
        if (c < lo || c >= hi) continue;
        int r = row[i];
        float nw = (1.0f - ALPHA) * dinv[r] * ew[i] * dinv[c];
        union { __half h; unsigned short u; } cv;
        cv.h = __float2half(nw);
        int pos = rp[c] + (int)rank[i];
        edges[pos] = ((unsigned)cv.u << 17) | (unsigned)r;
    }
}

// ---- W^T fp16 precompute for input GEMM (padded K=320) ----------------
__global__ void wt_k(const float* __restrict__ Win, f16* __restrict__ Wt) {
    int i = blockIdx.x * blockDim.x + threadIdx.x;  // 64*320
    if (i < 64 * 320) {
        int c = i / 320, k = i - c * 320;
        Wt[i] = (k < FIN) ? (f16)Win[k * 64 + c] : (f16)0.0f;
    }
}

// ---- input GEMM: x0h = relu(x @ W_in + b_in) via MFMA fp16 ------------
__global__ __launch_bounds__(256) void gemm_in_k(const float* __restrict__ x,
                                                 const f16* __restrict__ Wt,
                                                 const float* __restrict__ bin,
                                                 __half* __restrict__ x0h, int n) {
    __shared__ f16 As[64 * 72];  // x chunk tile (64 nodes x 64 k), pad 8
    int t = threadIdx.x, lane = t & 63, wv = t >> 6;
    int node0 = blockIdx.x * 64;
    int lr = lane & 15, kg = lane >> 4;
    f32x4 acc0 = {0, 0, 0, 0}, acc1 = {0, 0, 0, 0}, acc2 = {0, 0, 0, 0}, acc3 = {0, 0, 0, 0};
    int fi = t & 15;
    for (int c = 0; c < 5; ++c) {
        __syncthreads();
#pragma unroll
        for (int it = 0; it < 4; ++it) {
            int row = (t >> 4) + it * 16;
            int rr = node0 + row;
            rr = (rr < n) ? rr : (n - 1);
            int kbase = c * 64 + fi * 4;
            float4 v = make_float4(0.f, 0.f, 0.f, 0.f);
            if (kbase < FIN)
                v = *reinterpret_cast<const float4*>(x + (size_t)rr * FIN + kbase);
            union { float2 f2; f16 h[4]; } u;
            u.h[0] = (f16)v.x; u.h[1] = (f16)v.y; u.h[2] = (f16)v.z; u.h[3] = (f16)v.w;
            *reinterpret_cast<float2*>(As + row * 72 + fi * 4) = u.f2;
        }
        __syncthreads();
#pragma unroll
        for (int ks = 0; ks < 2; ++ks) {
            f16x8 a = *(const f16x8*)(As + (wv * 16 + lr) * 72 + ks * 32 + kg * 8);
            const f16* wb = Wt + c * 64 + ks * 32 + kg * 8;
            f16x8 b0 = *(const f16x8*)(wb + (0 * 16 + lr) * 320);
            f16x8 b1 = *(const f16x8*)(wb + (1 * 16 + lr) * 320);
            f16x8 b2 = *(const f16x8*)(wb + (2 * 16 + lr) * 320);
            f16x8 b3 = *(const f16x8*)(wb + (3 * 16 + lr) * 320);
            acc0 = __builtin_amdgcn_mfma_f32_16x16x32_f16(a, b0, acc0, 0, 0, 0);
            acc1 = __builtin_amdgcn_mfma_f32_16x16x32_f16(a, b1, acc1, 0, 0, 0);
            acc2 = __builtin_amdgcn_mfma_f32_16x16x32_f16(a, b2, acc2, 0, 0, 0);
            acc3 = __builtin_amdgcn_mfma_f32_16x16x32_f16(a, b3, acc3, 0, 0, 0);
        }
    }
    float bi0 = bin[0 * 16 + lr], bi1 = bin[1 * 16 + lr];
    float bi2 = bin[2 * 16 + lr], bi3 = bin[3 * 16 + lr];
    f16 ov[4][4];
#pragma unroll
    for (int r = 0; r < 4; ++r) {
        ov[0][r] = (f16)fmaxf(acc0[r] + bi0, 0.f);
        ov[1][r] = (f16)fmaxf(acc1[r] + bi1, 0.f);
        ov[2][r] = (f16)fmaxf(acc2[r] + bi2, 0.f);
        ov[3][r] = (f16)fmaxf(acc3[r] + bi3, 0.f);
    }
    __syncthreads();
#pragma unroll
    for (int cg = 0; cg < 4; ++cg)
#pragma unroll
        for (int r = 0; r < 4; ++r)
            As[(wv * 16 + kg * 4 + r) * 72 + cg * 16 + lr] = ov[cg][r];
    __syncthreads();
#pragma unroll
    for (int it = 0; it < 2; ++it) {
        int idx = t + it * 256;
        int row = idx >> 3, ch = idx & 7;
        int node = node0 + row;
        if (node < n)
            ((float4*)(x0h + (size_t)node * 64))[ch] =
                *reinterpret_cast<const float4*>(As + row * 72 + ch * 8);
    }
}

// ---- fused layer: group-per-node gather -> LDS z -> MFMA + residual ----
__global__ __launch_bounds__(256) void layer_k(const int* __restrict__ rp,
                                               const unsigned* __restrict__ edges,
                                               const float* __restrict__ dinv,
                                               const __half* __restrict__ x0h,
                                               const __half* __restrict__ hin,
                                               __half* __restrict__ hout,
                                               const float* __restrict__ Wl,
                                               float beta, int n) {
    __shared__ f16 As[64 * 72];  // z tile
    __shared__ f16 Bs[64 * 72];  // W^T tile
    int t = threadIdx.x, lane = t & 63, wv = t >> 6;
    int node0 = blockIdx.x * 64;
    for (int i = t; i < 4096; i += 256) {
        int k = i >> 6, c = i & 63;
        Bs[c * 72 + k] = (f16)Wl[i];
    }
    int g = lane >> 3, c8 = lane & 7;
#pragma unroll
    for (int pass = 0; pass < 2; ++pass) {
        int row = pass * 32 + wv * 8 + g;
        int node = node0 + row;
        int nd = (node < n) ? node : (n - 1);
        int j = rp[nd], end = (node < n) ? rp[nd + 1] : j;
        float a0[8], a1[8];
#pragma unroll
        for (int i = 0; i < 8; ++i) { a0[i] = 0.f; a1[i] = 0.f; }
        while (__any(j < end)) {
            bool v0 = j < end, v1 = (j + 1) < end;
            unsigned e0 = edges[v0 ? j : 0];
            unsigned e1 = edges[v1 ? (j + 1) : 0];
            float w0 = v0 ? wdec(e0) : 0.f;
            float w1 = v1 ? wdec(e1) : 0.f;
            float4 r0 = ((const float4*)(hin + (size_t)(e0 & 0x1FFFF) * 64))[c8];
            float4 r1 = ((const float4*)(hin + (size_t)(e1 & 0x1FFFF) * 64))[c8];
            float f0[8], f1[8];
            unpack8(r0, f0);
            unpack8(r1, f1);
#pragma unroll
            for (int i = 0; i < 8; ++i) {
                a0[i] = fmaf(w0, f0[i], a0[i]);
                a1[i] = fmaf(w1, f1[i], a1[i]);
            }
            j += 2;
        }
        float di = dinv[nd];
        float c1 = (1.0f - ALPHA) * di * di;
        float4 hs4 = ((const float4*)(hin + (size_t)nd * 64))[c8];
        float4 xs4 = ((const float4*)(x0h + (size_t)nd * 64))[c8];
        float hf[8], xf[8];
        unpack8(hs4, hf);
        unpack8(xs4, xf);
        f16x8 zv8;
#pragma unroll
        for (int i = 0; i < 8; ++i)
            zv8[i] = (f16)fmaf(ALPHA, xf[i], fmaf(c1, hf[i], a0[i] + a1[i]));
        *(f16x8*)(As + row * 72 + c8 * 8) = zv8;
    }
    __syncthreads();
    int lr = lane & 15, kg = lane >> 4;
    f32x4 acc0 = {0, 0, 0, 0}, acc1 = {0, 0, 0, 0}, acc2 = {0, 0, 0, 0}, acc3 = {0, 0, 0, 0};
    f16x8 af0 = *(const f16x8*)(As + (wv * 16 + lr) * 72 + kg * 8);
    f16x8 af1 = *(const f16x8*)(As + (wv * 16 + lr) * 72 + 32 + kg * 8);
    {
        f16x8 b0 = *(const f16x8*)(Bs + (0 * 16 + lr) * 72 + kg * 8);
        f16x8 b1 = *(const f16x8*)(Bs + (0 * 16 + lr) * 72 + 32 + kg * 8);
        acc0 = __builtin_amdgcn_mfma_f32_16x16x32_f16(af0, b0, acc0, 0, 0, 0);
        acc0 = __builtin_amdgcn_mfma_f32_16x16x32_f16(af1, b1, acc0, 0, 0, 0);
    }
    {
        f16x8 b0 = *(const f16x8*)(Bs + (1 * 16 + lr) * 72 + kg * 8);
        f16x8 b1 = *(const f16x8*)(Bs + (1 * 16 + lr) * 72 + 32 + kg * 8);
        acc1 = __builtin_amdgcn_mfma_f32_16x16x32_f16(af0, b0, acc1, 0, 0, 0);
        acc1 = __builtin_amdgcn_mfma_f32_16x16x32_f16(af1, b1, acc1, 0, 0, 0);
    }
    {
        f16x8 b0 = *(const f16x8*)(Bs + (2 * 16 + lr) * 72 + kg * 8);
        f16x8 b1 = *(const f16x8*)(Bs + (2 * 16 + lr) * 72 + 32 + kg * 8);
        acc2 = __builtin_amdgcn_mfma_f32_16x16x32_f16(af0, b0, acc2, 0, 0, 0);
        acc2 = __builtin_amdgcn_mfma_f32_16x16x32_f16(af1, b1, acc2, 0, 0, 0);
    }
    {
        f16x8 b0 = *(const f16x8*)(Bs + (3 * 16 + lr) * 72 + kg * 8);
        f16x8 b1 = *(const f16x8*)(Bs + (3 * 16 + lr) * 72 + 32 + kg * 8);
        acc3 = __builtin_amdgcn_mfma_f32_16x16x32_f16(af0, b0, acc3, 0, 0, 0);
        acc3 = __builtin_amdgcn_mfma_f32_16x16x32_f16(af1, b1, acc3, 0, 0, 0);
    }
    float omb = 1.0f - beta;
    f16 ov[4][4];
#pragma unroll
    for (int cg = 0; cg < 4; ++cg) {
        f32x4 acc = (cg == 0) ? acc0 : (cg == 1) ? acc1 : (cg == 2) ? acc2 : acc3;
        int col = cg * 16 + lr;
#pragma unroll
        for (int r = 0; r < 4; ++r) {
            float zv = (float)As[(wv * 16 + kg * 4 + r) * 72 + col];
            ov[cg][r] = (f16)fmaxf(fmaf(beta, acc[r], omb * zv), 0.f);
        }
    }
    __syncthreads();
#pragma unroll
    for (int cg = 0; cg < 4; ++cg)
#pragma unroll
        for (int r = 0; r < 4; ++r)
            As[(wv * 16 + kg * 4 + r) * 72 + cg * 16 + lr] = ov[cg][r];
    __syncthreads();
#pragma unroll
    for (int it = 0; it < 2; ++it) {
        int idx = t + it * 256;
        int row = idx >> 3, ch = idx & 7;
        int node = node0 + row;
        if (node < n)
            ((float4*)(hout + (size_t)node * 64))[ch] =
                *reinterpret_cast<const float4*>(As + row * 72 + ch * 8);
    }
}

// ---- output GEMM: out = h @ W_out + b_out -----------------------------
__global__ __launch_bounds__(256) void gemm_out_k(const __half* __restrict__ h,
                                                  const float* __restrict__ Wout,
                                                  const float* __restrict__ bout,
                                                  float* __restrict__ out, int n) {
    __shared__ float hs[64][65];
    __shared__ float Ws[64 * NOUT];
    __shared__ float bs[NOUT];
    int t = threadIdx.x;
    for (int i = t; i < 64 * NOUT; i += 256) Ws[i] = Wout[i];
    if (t < NOUT) bs[t] = bout[t];
    int base = blockIdx.x * 64;
    int lim = min(64, n - base);
    for (int i = t; i < 64 * 32; i += 256) {
        int r = i >> 5, c2 = (i & 31) * 2;
        float2 v = make_float2(0.f, 0.f);
        if (r < lim) {
            __half2 hv = reinterpret_cast<const __half2*>(
                h + (size_t)(base + r) * 64)[i & 31];
            v = __half22float2(hv);
        }
        hs[r][c2] = v.x;
        hs[r][c2 + 1] = v.y;
    }
    __syncthreads();
#pragma unroll
    for (int q = 0; q < 5; ++q) {
        int of = t + 256 * q;
        int nd = of / NOUT, o = of - nd * NOUT;
        float acc = bs[o];
#pragma unroll
        for (int k = 0; k < 64; ++k) acc = fmaf(hs[nd][k], Ws[k * NOUT + o], acc);
        if (nd < lim) out[(size_t)(base + nd) * NOUT + o] = acc;
    }
}

extern "C" void kernel_launch(void* const* d_in, const int* in_sizes, int n_in,
                              void* d_out, int out_size, void* d_ws, size_t ws_size,
                              hipStream_t stream) {
    const float* x    = (const float*)d_in[0];
    const int*   ei   = (const int*)d_in[1];
    const float* ew   = (const float*)d_in[2];
    const float* Win  = (const float*)d_in[3];
    const float* bin  = (const float*)d_in[4];
    const float* cw   = (const float*)d_in[5];
    const float* Wout = (const float*)d_in[6];
    const float* bout = (const float*)d_in[7];

    const int n = in_sizes[0] / FIN;          // 100000
    const int e = in_sizes[2];                // 1600000
    const int L = in_sizes[5] / (HID * HID);  // 8
    const int* row = ei;
    const int* col = ei + e;

    size_t off = 0;
    auto alloc = [&](size_t bytes) -> char* {
        char* q = (char*)d_ws + off;
        off = (off + bytes + 255) & ~(size_t)255;
        return q;
    };
    __half* x0h  = (__half*)alloc((size_t)n * HID * 2);
    __half* hA   = (__half*)alloc((size_t)n * HID * 2);
    __half* hB   = (__half*)alloc((size_t)n * HID * 2);
    unsigned* edges = (unsigned*)alloc((size_t)e * 4);
    unsigned char* rank = (unsigned char*)alloc((size_t)e);
    unsigned* packed = (unsigned*)alloc((size_t)n * 4);
    float* dinv  = (float*)alloc((size_t)n * 4);
    int*   rp    = (int*)alloc((size_t)(n + 1) * 4);
    int*   bsum  = (int*)alloc(1024 * 4);
    f16*   Wt    = (f16*)alloc((size_t)64 * 320 * 2);

    const int nb = (n + 1023) / 1024;
    const int ntile = (n + 63) / 64;

    init_k<<<(n + 255) / 256, 256, 0, stream>>>(packed, n);
    accum_k<<<(e + 255) / 256, 256, 0, stream>>>(col, ew, packed, rank, e);
    unpackscan_k<<<nb, 1024, 0, stream>>>(packed, dinv, bsum, n);
    scan2_k<<<1, 1, 0, stream>>>(bsum, nb, rp, n, e);
    scan3_k<<<nb, 1024, 0, stream>>>(packed, bsum, rp, n);
    fill_k<<<1024, 256, 0, stream>>>(row, col, ew, dinv, rp, rank, edges, e, n);

    wt_k<<<(64 * 320 + 255) / 256, 256, 0, stream>>>(Win, Wt);
    gemm_in_k<<<ntile, 256, 0, stream>>>(x, Wt, bin, x0h, n);

    const __half* hin = x0h;
    __half* hout = hA;
    for (int l = 0; l < L; ++l) {
        float beta = (float)log(0.5 / (double)(l + 1) + 1.0);
        layer_k<<<ntile, 256, 0, stream>>>(rp, edges, dinv, x0h, hin, hout,
                                           cw + (size_t)l * HID * HID, beta, n);
        hin = hout;
        hout = (hout == hA) ? hB : hA;
    }
    gemm_out_k<<<(n + 63) / 64, 256, 0, stream>>>(hin, Wout, bout, (float*)d_out, n);
}